// Round 8
// baseline (318.111 us; speedup 1.0000x reference)
//
#include <hip/hip_runtime.h>
#include <hip/hip_fp16.h>
#include <math.h>

// ---------------------------------------------------------------------------
// GCN (3-layer feature + 3-layer attention) + segment softmax + attention
// pooling + MLP.
// R14: fusedl1/t3gemm were GRID-parallelism-bound: 782 blocks = 3.05/CU,
//     LDS-capped at 3 resident -> runtime ~= one block's serial latency
//     chain (42us @ 10% MfmaUtil, all pipes idle). Halve tile to BM=32:
//     1563 blocks, fusedl1 LDS 52->26KB (6 blocks/CU), per-block chain
//     halves, 2x independent chains overlap per CU. GEMM2b re-split so
//     all 4 waves stay active. Same arithmetic -> absmax unchanged.
// ---------------------------------------------------------------------------

#define DIN 128
#define FH  128
#define DOUT 256
#define NBUK 128
#define SUBN 512
#define IMGCAP 16384
#define ECAP 16384

typedef float f4 __attribute__((ext_vector_type(4)));
typedef float f32x4 __attribute__((ext_vector_type(4)));
typedef _Float16 h8v __attribute__((ext_vector_type(8)));
typedef _Float16 h4v __attribute__((ext_vector_type(4)));

// ---------------- graph prep ----------------

// scan1 also produces dinv (rsqrt of degree+1) since it already loads cnt.
__global__ __launch_bounds__(256) void scan1_kernel(const int* __restrict__ cnt,
        int* __restrict__ bsum, float* __restrict__ dinv, int n) {
    __shared__ int sm[256];
    int tid = threadIdx.x;
    int base = blockIdx.x * 512;
    int a = (base + tid < n) ? cnt[base + tid] : 0;
    int b = (base + 256 + tid < n) ? cnt[base + 256 + tid] : 0;
    if (base + tid < n)       dinv[base + tid]       = rsqrtf((float)(a + 1));
    if (base + 256 + tid < n) dinv[base + 256 + tid] = rsqrtf((float)(b + 1));
    sm[tid] = a + b;
    __syncthreads();
    for (int off = 128; off > 0; off >>= 1) {
        if (tid < off) sm[tid] += sm[tid + off];
        __syncthreads();
    }
    if (tid == 0) bsum[blockIdx.x] = sm[0];
}

__global__ void scan2_kernel(const int* __restrict__ bsum, int* __restrict__ boff,
                             int* __restrict__ rpN, int nb) {
    if (threadIdx.x == 0) {
        int run = 0;
        for (int i = 0; i < nb; ++i) { boff[i] = run; run += bsum[i]; }
        *rpN = run;
    }
}

__global__ __launch_bounds__(256) void scan3_kernel(const int* __restrict__ cnt,
        const int* __restrict__ boff, int* __restrict__ rp, int n) {
    __shared__ int sm[256];
    int tid = threadIdx.x;
    int base = blockIdx.x * 512;
    int i0 = base + 2 * tid;
    int c0 = (i0 < n) ? cnt[i0] : 0;
    int c1 = (i0 + 1 < n) ? cnt[i0 + 1] : 0;
    int ps = c0 + c1;
    sm[tid] = ps;
    __syncthreads();
    for (int off = 1; off < 256; off <<= 1) {
        int v = (tid >= off) ? sm[tid - off] : 0;
        __syncthreads();
        sm[tid] += v;
        __syncthreads();
    }
    int excl = sm[tid] - ps + boff[blockIdx.x];
    if (i0 < n) rp[i0] = excl;
    if (i0 + 1 < n) rp[i0 + 1] = excl + c0;
}

// Pass A: block-local counting sort by bucket in LDS, then coalesced
// burst-out to per-bucket frontiers (bases at b*ECAP).
__global__ __launch_bounds__(256) void ebucket_kernel(const int* __restrict__ src,
        const int* __restrict__ dst, int* __restrict__ bcur,
        unsigned long long* __restrict__ entries, int E, int shift) {
    __shared__ int lcnt[NBUK], lscan[NBUK], lbase[NBUK], lcur[NBUK];
    __shared__ unsigned long long stage[2048];
    const int tid = threadIdx.x;
    const int e0 = blockIdx.x * 2048;
    if (tid < NBUK) { lcnt[tid] = 0; lcur[tid] = 0; }
    __syncthreads();
    int s_[8], d_[8];
    #pragma unroll
    for (int k = 0; k < 8; ++k) {
        int e = e0 + k * 256 + tid;
        if (e < E) {
            s_[k] = src[e];
            d_[k] = dst[e];
            atomicAdd(&lcnt[d_[k] >> shift], 1);
        } else {
            d_[k] = -1;
        }
    }
    __syncthreads();
    // exclusive scan over NBUK counters (Hillis-Steele, 128 lanes active)
    if (tid < NBUK) lscan[tid] = lcnt[tid];
    __syncthreads();
    for (int off = 1; off < NBUK; off <<= 1) {
        int v = 0;
        if (tid < NBUK && tid >= off) v = lscan[tid - off];
        __syncthreads();
        if (tid < NBUK) lscan[tid] += v;
        __syncthreads();
    }
    if (tid < NBUK) {
        lscan[tid] -= lcnt[tid];   // inclusive -> exclusive
        lbase[tid] = lcnt[tid] ? atomicAdd(&bcur[tid], lcnt[tid]) : 0;
    }
    __syncthreads();
    // scatter into LDS stage, sorted by bucket
    #pragma unroll
    for (int k = 0; k < 8; ++k) {
        if (d_[k] >= 0) {
            int b = d_[k] >> shift;
            int pos = lscan[b] + atomicAdd(&lcur[b], 1);
            stage[pos] = ((unsigned long long)(unsigned)d_[k] << 32) | (unsigned)s_[k];
        }
    }
    __syncthreads();
    // coalesced burst-out: LDS position i -> bucket via binary search
    const int total = min(2048, E - e0);
    for (int i = tid; i < total; i += 256) {
        int lo = 0, hi = NBUK - 1;
        while (lo < hi) {
            int mid = (lo + hi + 1) >> 1;
            if (lscan[mid] <= i) lo = mid; else hi = mid - 1;
        }
        int idx = lbase[lo] + (i - lscan[lo]);
        if (idx < (lo + 1) * ECAP)   // capacity guard (never hit: 91 sigma)
            entries[(size_t)idx] = stage[i];
    }
}

// Degree histogram from bucketed entries: one block per bucket, LDS
// histogram, coalesced cnt write.
__global__ __launch_bounds__(512) void ecount_kernel(
        const unsigned long long* __restrict__ entries,
        const int* __restrict__ bcur, int* __restrict__ cnt, int n, int shift) {
    __shared__ int hist[SUBN];
    const int b = blockIdx.x;
    const int n0 = b << shift;
    if (n0 >= n) return;
    const int n1 = min(n0 + SUBN, n);
    const int tid = threadIdx.x;
    hist[tid] = 0;
    __syncthreads();
    const size_t ebase = (size_t)b * ECAP;
    const int len = min(bcur[b] - b * ECAP, ECAP);
    for (int i = tid; i < len; i += 512)
        atomicAdd(&hist[(int)(entries[ebase + i] >> 32) - n0], 1);
    __syncthreads();
    if (n0 + tid < n1) cnt[n0 + tid] = hist[tid];
}

// Pass B: per-bucket counting sort fully in LDS, contiguous stream-out to cn.
__global__ __launch_bounds__(512) void ecsr_kernel(
        const unsigned long long* __restrict__ entries,
        const int* __restrict__ rp, const float* __restrict__ dinv,
        long long* __restrict__ cn, int n, int shift) {
    __shared__ long long img[IMGCAP];
    __shared__ int hist[SUBN];
    __shared__ int lcur[SUBN];
    __shared__ int sm[SUBN];
    __shared__ float dl[SUBN];
    const int b = blockIdx.x;
    const int n0 = b << shift;
    if (n0 >= n) return;
    const int n1 = min(n0 + (1 << shift), n);
    const int base = rp[n0];
    const int len  = rp[n1] - base;
    const size_t ebase = (size_t)b * ECAP;
    const int tid = threadIdx.x;
    hist[tid] = 0;
    lcur[tid] = 0;
    if (n0 + tid < n1) dl[tid] = dinv[n0 + tid];
    __syncthreads();
    for (int i = tid; i < len; i += 512)
        atomicAdd(&hist[(int)(entries[ebase + i] >> 32) - n0], 1);
    __syncthreads();
    int v = hist[tid];
    sm[tid] = v;
    __syncthreads();
    for (int off = 1; off < SUBN; off <<= 1) {
        int t = (tid >= off) ? sm[tid - off] : 0;
        __syncthreads();
        sm[tid] += t;
        __syncthreads();
    }
    hist[tid] = sm[tid] - v;
    __syncthreads();
    const bool fits = (len <= IMGCAP);
    for (int i = tid; i < len; i += 512) {
        unsigned long long e = entries[ebase + i];
        int d  = (int)(e >> 32) - n0;
        int sx = (int)(unsigned)(e & 0xffffffffu);
        int pos = hist[d] + atomicAdd(&lcur[d], 1);
        float w = dinv[sx] * dl[d];
        long long val = (long long)(unsigned)sx | ((long long)__float_as_int(w) << 32);
        if (fits) img[pos] = val;
        else      cn[base + pos] = val;
    }
    __syncthreads();
    if (fits)
        for (int i = tid; i < len; i += 512) cn[base + i] = img[i];
}

__global__ void gstart_kernel(const int* __restrict__ batch, int* __restrict__ gstart,
                              int n, int g) {
    int t = threadIdx.x;
    if (t > g) return;
    int lo = 0, hi = n;
    while (lo < hi) {
        int mid = (lo + hi) >> 1;
        if (batch[mid] < t) lo = mid + 1; else hi = mid;
    }
    gstart[t] = lo;
}

// fp32 -> fp16 convert (8 elems / thread)
__global__ void cvt16_kernel(const float* __restrict__ in, __half* __restrict__ outh,
                             long n8) {
    long i = (long)blockIdx.x * 256 + threadIdx.x;
    if (i >= n8) return;
    f4 a = ((const f4*)in)[2 * i];
    f4 b = ((const f4*)in)[2 * i + 1];
    __half2 h0 = __float22half2_rn(make_float2(a.x, a.y));
    __half2 h1 = __float22half2_rn(make_float2(a.z, a.w));
    __half2 h2 = __float22half2_rn(make_float2(b.x, b.y));
    __half2 h3 = __float22half2_rn(make_float2(b.z, b.w));
    uint4 st;
    st.x = *(unsigned*)&h0; st.y = *(unsigned*)&h1;
    st.z = *(unsigned*)&h2; st.w = *(unsigned*)&h3;
    ((uint4*)outh)[i] = st;
}

// ---------------- weight prep: split-fp16 transpose ----------------

__device__ __forceinline__ void wsplit(const float* __restrict__ W,
        _Float16* __restrict__ Th, _Float16* __restrict__ Tl,
        int fin, int fout, int i) {
    int r = i / fout, c = i % fout;
    float w = W[i];
    _Float16 h = (_Float16)w;
    Th[c * fin + r] = h;
    Tl[c * fin + r] = (_Float16)(w - (float)h);
}

// WT half-offsets: W1h=0 W1l=16384 W2h=32768 W2l=49152 W3h=65536 W3l=81920
//                  A1h=98304 A1l=106496 A2h=114688 A2l=116736  (total 118784)
__global__ __launch_bounds__(256) void wprep_kernel(const float* __restrict__ W1,
        const float* __restrict__ W2, const float* __restrict__ W3,
        const float* __restrict__ A1, const float* __restrict__ A2,
        _Float16* __restrict__ T, int* __restrict__ bcur) {
    int i = blockIdx.x * 256 + threadIdx.x;
    if (blockIdx.x == 0 && threadIdx.x < NBUK) bcur[threadIdx.x] = threadIdx.x * ECAP;
    if (i < 16384)       wsplit(W1, T,          T + 16384,  128, 128, i);
    else if (i < 32768)  wsplit(W2, T + 32768,  T + 49152,  128, 128, i - 16384);
    else if (i < 49152)  wsplit(W3, T + 65536,  T + 81920,  128, 128, i - 32768);
    else if (i < 57344)  wsplit(A1, T + 98304,  T + 106496, 128, 64,  i - 49152);
    else if (i < 59392)  wsplit(A2, T + 114688, T + 116736, 64,  32,  i - 57344);
}

// ---------------- fused layer-1 linears (split-fp16 MFMA), BM=32 ----------
// stage Y->LDS | sync
// GEMM1b: accA = Y@A1 -> a1 h/l -> side buffer (frees accA)
// GEMM1a: accF = Y@W1 | sync (Y reads done)
// write f1 h/l -> Y's LDS (alias) | sync
// GEMM2a: t2 = f1@W2 (col-split) ; GEMM2b: u2 = a1@A2 (quad-split)

__global__ __launch_bounds__(256) void fusedl1_kernel(const float* __restrict__ Y,
        const _Float16* __restrict__ T, const float* __restrict__ b1,
        const float* __restrict__ ba1, __half* __restrict__ t2,
        __half* __restrict__ u2, int n) {
    constexpr int BM    = 32;
    constexpr int LSTR  = 136;
    constexpr int LSTRB = 68;
    __shared__ _Float16 L1[BM * LSTR];     // Yh, then f1 high (alias)
    __shared__ _Float16 L2[BM * LSTR];     // Yl, then f1 low  (alias)
    __shared__ _Float16 Ah_[BM * LSTRB];   // a1 high
    __shared__ _Float16 Al_[BM * LSTRB];   // a1 low
    const int tid  = threadIdx.x;
    const int w    = tid >> 6;
    const int lane = tid & 63;
    const int bk   = (lane >> 4) * 8;
    const int cl   = lane & 15;
    const long row0 = (long)blockIdx.x * BM;

    // stage Y -> LDS, split fp32 -> fp16 h/l (BM*32 float4s, 4/thread)
    for (int i = tid; i < BM * 32; i += 256) {
        int r = i >> 5, c4 = i & 31;
        long gr = row0 + r;
        float4 v = {0.f, 0.f, 0.f, 0.f};
        if (gr < n) v = *(const float4*)&Y[gr * 128 + c4 * 4];
        _Float16 h0 = (_Float16)v.x, h1 = (_Float16)v.y;
        _Float16 h2 = (_Float16)v.z, h3 = (_Float16)v.w;
        *(h4v*)&L1[r * LSTR + c4 * 4] = (h4v){h0, h1, h2, h3};
        *(h4v*)&L2[r * LSTR + c4 * 4] =
            (h4v){(_Float16)(v.x - (float)h0), (_Float16)(v.y - (float)h1),
                  (_Float16)(v.z - (float)h2), (_Float16)(v.w - (float)h3)};
    }
    __syncthreads();

    // ---- GEMM1b FIRST: accA = Y@A1 (wave w owns cols [w*16,w*16+16)),
    // write a1 immediately (short reg life)
    {
        const _Float16* A1h = T + 98304;
        const _Float16* A1l = T + 106496;
        const int ca = w * 16 + cl;
        h8v A1hf[4], A1lf[4];
        #pragma unroll
        for (int kk = 0; kk < 4; ++kk) {
            A1hf[kk] = *(const h8v*)&A1h[ca * 128 + kk * 32 + bk];
            A1lf[kk] = *(const h8v*)&A1l[ca * 128 + kk * 32 + bk];
        }
        f32x4 accA[2];
        accA[0] = (f32x4){0.f,0.f,0.f,0.f};
        accA[1] = (f32x4){0.f,0.f,0.f,0.f};
        #pragma unroll
        for (int rt = 0; rt < 2; ++rt) {
            int r = rt * 16 + cl;
            #pragma unroll
            for (int kk = 0; kk < 4; ++kk) {
                h8v ah = *(const h8v*)&L1[r * LSTR + kk * 32 + bk];
                h8v al = *(const h8v*)&L2[r * LSTR + kk * 32 + bk];
                accA[rt] = __builtin_amdgcn_mfma_f32_16x16x32_f16(ah, A1hf[kk], accA[rt], 0, 0, 0);
                accA[rt] = __builtin_amdgcn_mfma_f32_16x16x32_f16(ah, A1lf[kk], accA[rt], 0, 0, 0);
                accA[rt] = __builtin_amdgcn_mfma_f32_16x16x32_f16(al, A1hf[kk], accA[rt], 0, 0, 0);
            }
        }
        float bv = ba1[ca];
        #pragma unroll
        for (int rt = 0; rt < 2; ++rt) {
            int rowb = rt * 16 + (lane >> 4) * 4;
            #pragma unroll
            for (int j = 0; j < 4; ++j) {
                float v = fmaxf(accA[rt][j] + bv, 0.f);
                _Float16 h = (_Float16)v;
                Ah_[(rowb + j) * LSTRB + ca] = h;
                Al_[(rowb + j) * LSTRB + ca] = (_Float16)(v - (float)h);
            }
        }
    }

    // ---- GEMM1a: accF = Y@W1 (wave w owns cols [w*32, w*32+32))
    f32x4 accF[2][2];
    {
        const _Float16* W1h = T;
        const _Float16* W1l = T + 16384;
        h8v Bh[2][4], Bl[2][4];
        #pragma unroll
        for (int ct = 0; ct < 2; ++ct) {
            int c = w * 32 + ct * 16 + cl;
            #pragma unroll
            for (int kk = 0; kk < 4; ++kk) {
                Bh[ct][kk] = *(const h8v*)&W1h[c * 128 + kk * 32 + bk];
                Bl[ct][kk] = *(const h8v*)&W1l[c * 128 + kk * 32 + bk];
            }
        }
        #pragma unroll
        for (int rt = 0; rt < 2; ++rt)
            #pragma unroll
            for (int ct = 0; ct < 2; ++ct) accF[rt][ct] = (f32x4){0.f,0.f,0.f,0.f};
        #pragma unroll
        for (int rt = 0; rt < 2; ++rt) {
            int r = rt * 16 + cl;
            #pragma unroll
            for (int kk = 0; kk < 4; ++kk) {
                h8v ah = *(const h8v*)&L1[r * LSTR + kk * 32 + bk];
                h8v al = *(const h8v*)&L2[r * LSTR + kk * 32 + bk];
                #pragma unroll
                for (int ct = 0; ct < 2; ++ct) {
                    accF[rt][ct] = __builtin_amdgcn_mfma_f32_16x16x32_f16(ah, Bh[ct][kk], accF[rt][ct], 0, 0, 0);
                    accF[rt][ct] = __builtin_amdgcn_mfma_f32_16x16x32_f16(ah, Bl[ct][kk], accF[rt][ct], 0, 0, 0);
                    accF[rt][ct] = __builtin_amdgcn_mfma_f32_16x16x32_f16(al, Bh[ct][kk], accF[rt][ct], 0, 0, 0);
                }
            }
        }
    }
    __syncthreads();   // all Y reads complete -> safe to overwrite L1/L2

    // ---- write f1 = relu(accF+b1) -> L1/L2 (alias)
    #pragma unroll
    for (int rt = 0; rt < 2; ++rt) {
        int rowb = rt * 16 + (lane >> 4) * 4;
        #pragma unroll
        for (int ct = 0; ct < 2; ++ct) {
            int col = w * 32 + ct * 16 + cl;
            float bv = b1[col];
            #pragma unroll
            for (int j = 0; j < 4; ++j) {
                float v = fmaxf(accF[rt][ct][j] + bv, 0.f);
                _Float16 h = (_Float16)v;
                L1[(rowb + j) * LSTR + col] = h;
                L2[(rowb + j) * LSTR + col] = (_Float16)(v - (float)h);
            }
        }
    }
    __syncthreads();

    // ---- GEMM2a: t2 = f1@W2 (fp16 out; wave w owns cols [w*32, w*32+32))
    {
        const _Float16* W2h = T + 32768;
        const _Float16* W2l = T + 49152;
        h8v Bh[2][4], Bl[2][4];
        #pragma unroll
        for (int ct = 0; ct < 2; ++ct) {
            int c = w * 32 + ct * 16 + cl;
            #pragma unroll
            for (int kk = 0; kk < 4; ++kk) {
                Bh[ct][kk] = *(const h8v*)&W2h[c * 128 + kk * 32 + bk];
                Bl[ct][kk] = *(const h8v*)&W2l[c * 128 + kk * 32 + bk];
            }
        }
        f32x4 acc[2][2];
        #pragma unroll
        for (int rt = 0; rt < 2; ++rt)
            #pragma unroll
            for (int ct = 0; ct < 2; ++ct) acc[rt][ct] = (f32x4){0.f,0.f,0.f,0.f};
        #pragma unroll
        for (int rt = 0; rt < 2; ++rt) {
            int r = rt * 16 + cl;
            #pragma unroll
            for (int kk = 0; kk < 4; ++kk) {
                h8v ah = *(const h8v*)&L1[r * LSTR + kk * 32 + bk];
                h8v al = *(const h8v*)&L2[r * LSTR + kk * 32 + bk];
                #pragma unroll
                for (int ct = 0; ct < 2; ++ct) {
                    acc[rt][ct] = __builtin_amdgcn_mfma_f32_16x16x32_f16(ah, Bh[ct][kk], acc[rt][ct], 0, 0, 0);
                    acc[rt][ct] = __builtin_amdgcn_mfma_f32_16x16x32_f16(ah, Bl[ct][kk], acc[rt][ct], 0, 0, 0);
                    acc[rt][ct] = __builtin_amdgcn_mfma_f32_16x16x32_f16(al, Bh[ct][kk], acc[rt][ct], 0, 0, 0);
                }
            }
        }
        #pragma unroll
        for (int rt = 0; rt < 2; ++rt) {
            long rbase = row0 + rt * 16 + (lane >> 4) * 4;
            #pragma unroll
            for (int ct = 0; ct < 2; ++ct) {
                int col = w * 32 + ct * 16 + cl;
                #pragma unroll
                for (int j = 0; j < 4; ++j) {
                    long r = rbase + j;
                    if (r < n) t2[r * 128 + col] = __float2half(acc[rt][ct][j]);
                }
            }
        }
    }

    // ---- GEMM2b: u2 = a1@A2 (fp16 out; wave w owns row-half w&1,
    // col-half w>>1 of the 32x32 tile)
    {
        const _Float16* A2h = T + 114688;
        const _Float16* A2l = T + 116736;
        const int rowh = (w & 1) * 16;
        const int colh = (w >> 1) * 16;
        const int c = colh + cl;
        h8v Bh[2], Bl[2];
        #pragma unroll
        for (int kk = 0; kk < 2; ++kk) {
            Bh[kk] = *(const h8v*)&A2h[c * 64 + kk * 32 + bk];
            Bl[kk] = *(const h8v*)&A2l[c * 64 + kk * 32 + bk];
        }
        f32x4 acc = (f32x4){0.f,0.f,0.f,0.f};
        const int r = rowh + cl;
        #pragma unroll
        for (int kk = 0; kk < 2; ++kk) {
            h8v ah = *(const h8v*)&Ah_[r * LSTRB + kk * 32 + bk];
            h8v al = *(const h8v*)&Al_[r * LSTRB + kk * 32 + bk];
            acc = __builtin_amdgcn_mfma_f32_16x16x32_f16(ah, Bh[kk], acc, 0, 0, 0);
            acc = __builtin_amdgcn_mfma_f32_16x16x32_f16(ah, Bl[kk], acc, 0, 0, 0);
            acc = __builtin_amdgcn_mfma_f32_16x16x32_f16(al, Bh[kk], acc, 0, 0, 0);
        }
        long rbase = row0 + rowh + (lane >> 4) * 4;
        #pragma unroll
        for (int j = 0; j < 4; ++j) {
            long rr = rbase + j;
            if (rr < n) u2[rr * 32 + c] = __float2half(acc[j]);
        }
    }
}

// ---------------- t3 GEMM: t3 = f2[n,128] @ W3 (fp16 out), BM=32 ----------
__global__ __launch_bounds__(256) void t3gemm_kernel(const float* __restrict__ A,
        const _Float16* __restrict__ Wh, const _Float16* __restrict__ Wl,
        __half* __restrict__ C, int n) {
    constexpr int BM   = 32;
    constexpr int LSTR = 136;
    __shared__ _Float16 Ahs[BM * LSTR];
    __shared__ _Float16 Als[BM * LSTR];
    const int tid  = threadIdx.x;
    const int w    = tid >> 6;
    const int lane = tid & 63;
    const int bk   = (lane >> 4) * 8;
    const int cl   = lane & 15;
    const long row0 = (long)blockIdx.x * BM;

    for (int i = tid; i < BM * 32; i += 256) {
        int r = i >> 5, c4 = i & 31;
        long gr = row0 + r;
        float4 v = {0.f, 0.f, 0.f, 0.f};
        if (gr < n) v = *(const float4*)&A[gr * 128 + c4 * 4];
        _Float16 h0 = (_Float16)v.x, h1 = (_Float16)v.y;
        _Float16 h2 = (_Float16)v.z, h3 = (_Float16)v.w;
        *(h4v*)&Ahs[r * LSTR + c4 * 4] = (h4v){h0, h1, h2, h3};
        *(h4v*)&Als[r * LSTR + c4 * 4] =
            (h4v){(_Float16)(v.x - (float)h0), (_Float16)(v.y - (float)h1),
                  (_Float16)(v.z - (float)h2), (_Float16)(v.w - (float)h3)};
    }

    h8v Bh[2][4], Bl[2][4];
    #pragma unroll
    for (int ct = 0; ct < 2; ++ct) {
        int c = w * 32 + ct * 16 + cl;
        #pragma unroll
        for (int kk = 0; kk < 4; ++kk) {
            Bh[ct][kk] = *(const h8v*)&Wh[c * 128 + kk * 32 + bk];
            Bl[ct][kk] = *(const h8v*)&Wl[c * 128 + kk * 32 + bk];
        }
    }
    __syncthreads();

    f32x4 acc[2][2];
    #pragma unroll
    for (int rt = 0; rt < 2; ++rt)
        #pragma unroll
        for (int ct = 0; ct < 2; ++ct) acc[rt][ct] = (f32x4){0.f,0.f,0.f,0.f};
    #pragma unroll
    for (int rt = 0; rt < 2; ++rt) {
        int r = rt * 16 + cl;
        #pragma unroll
        for (int kk = 0; kk < 4; ++kk) {
            h8v ah = *(const h8v*)&Ahs[r * LSTR + kk * 32 + bk];
            h8v al = *(const h8v*)&Als[r * LSTR + kk * 32 + bk];
            #pragma unroll
            for (int ct = 0; ct < 2; ++ct) {
                acc[rt][ct] = __builtin_amdgcn_mfma_f32_16x16x32_f16(ah, Bh[ct][kk], acc[rt][ct], 0, 0, 0);
                acc[rt][ct] = __builtin_amdgcn_mfma_f32_16x16x32_f16(ah, Bl[ct][kk], acc[rt][ct], 0, 0, 0);
                acc[rt][ct] = __builtin_amdgcn_mfma_f32_16x16x32_f16(al, Bh[ct][kk], acc[rt][ct], 0, 0, 0);
            }
        }
    }
    #pragma unroll
    for (int rt = 0; rt < 2; ++rt) {
        long rbase = row0 + rt * 16 + (lane >> 4) * 4;
        #pragma unroll
        for (int ct = 0; ct < 2; ++ct) {
            int col = w * 32 + ct * 16 + cl;
            #pragma unroll
            for (int j = 0; j < 4; ++j) {
                long r = rbase + j;
                if (r < n) C[r * 128 + col] = __float2half(acc[rt][ct][j]);
            }
        }
    }
}

// ---------------- fp16-gather aggregation ----------------

__device__ __forceinline__ void hacc8(float acc[8], uint4 u, float w) {
    __half2 h; float2 f;
    h = *(__half2*)&u.x; f = __half22float2(h); acc[0] += w * f.x; acc[1] += w * f.y;
    h = *(__half2*)&u.y; f = __half22float2(h); acc[2] += w * f.x; acc[3] += w * f.y;
    h = *(__half2*)&u.z; f = __half22float2(h); acc[4] += w * f.x; acc[5] += w * f.y;
    h = *(__half2*)&u.w; f = __half22float2(h); acc[6] += w * f.x; acc[7] += w * f.y;
}

template<int F, bool BR>
__global__ __launch_bounds__(256) void aggh_kernel(const __half* __restrict__ tin,
        const float* __restrict__ bias, const float* __restrict__ dinv,
        const int* __restrict__ rp, const long long* __restrict__ cn,
        float* __restrict__ out, int n) {
    constexpr int LPR   = F / 8;
    constexpr int SLOTS = 64 / LPR;
    const int lane = threadIdx.x & 63;
    const int node = blockIdx.x * 4 + (threadIdx.x >> 6);
    if (node >= n) return;
    const int l    = lane % LPR;
    const int slot = lane / LPR;
    const uint4* base = (const uint4*)tin + l;
    const int e0 = rp[node], e1 = rp[node + 1];
    float acc[8] = {0.f, 0.f, 0.f, 0.f, 0.f, 0.f, 0.f, 0.f};
    if (slot == 0) {
        float di = dinv[node];
        uint4 u = base[(size_t)node * LPR];
        hacc8(acc, u, di * di);
    }
    int p = e0 + slot;
    for (; p + 3 * SLOTS < e1; p += 4 * SLOTS) {
        long long r0 = __builtin_nontemporal_load(cn + p);
        long long r1 = __builtin_nontemporal_load(cn + p + SLOTS);
        long long r2 = __builtin_nontemporal_load(cn + p + 2 * SLOTS);
        long long r3 = __builtin_nontemporal_load(cn + p + 3 * SLOTS);
        uint4 u0 = base[(size_t)(unsigned)r0 * LPR];
        uint4 u1 = base[(size_t)(unsigned)r1 * LPR];
        uint4 u2 = base[(size_t)(unsigned)r2 * LPR];
        uint4 u3 = base[(size_t)(unsigned)r3 * LPR];
        hacc8(acc, u0, __int_as_float((int)(r0 >> 32)));
        hacc8(acc, u1, __int_as_float((int)(r1 >> 32)));
        hacc8(acc, u2, __int_as_float((int)(r2 >> 32)));
        hacc8(acc, u3, __int_as_float((int)(r3 >> 32)));
    }
    for (; p + SLOTS < e1; p += 2 * SLOTS) {
        long long r0 = __builtin_nontemporal_load(cn + p);
        long long r1 = __builtin_nontemporal_load(cn + p + SLOTS);
        uint4 u0 = base[(size_t)(unsigned)r0 * LPR];
        uint4 u1 = base[(size_t)(unsigned)r1 * LPR];
        hacc8(acc, u0, __int_as_float((int)(r0 >> 32)));
        hacc8(acc, u1, __int_as_float((int)(r1 >> 32)));
    }
    if (p < e1) {
        long long r0 = __builtin_nontemporal_load(cn + p);
        uint4 u0 = base[(size_t)(unsigned)r0 * LPR];
        hacc8(acc, u0, __int_as_float((int)(r0 >> 32)));
    }
    #pragma unroll
    for (int off = 32; off >= LPR; off >>= 1) {
        #pragma unroll
        for (int j = 0; j < 8; ++j) acc[j] += __shfl_xor(acc[j], off);
    }
    if (slot == 0) {
        if (BR) {
            #pragma unroll
            for (int j = 0; j < 8; ++j)
                acc[j] = fmaxf(acc[j] + bias[l * 8 + j], 0.f);
        }
        f4 lo = {acc[0], acc[1], acc[2], acc[3]};
        f4 hi = {acc[4], acc[5], acc[6], acc[7]};
        float* o = out + (size_t)node * F + l * 8;
        __builtin_nontemporal_store(lo, (f4*)o);
        __builtin_nontemporal_store(hi, (f4*)(o + 4));
    }
}

// a2-aggregation (F=32) with fused a3 dot: wlin[node] = relu(agg+ba2) . A3
__global__ __launch_bounds__(256) void aggh32a_kernel(const __half* __restrict__ tin,
        const float* __restrict__ ba2, const float* __restrict__ A3,
        const float* __restrict__ dinv, const int* __restrict__ rp,
        const long long* __restrict__ cn, float* __restrict__ wlin, int n) {
    constexpr int LPR   = 4;
    constexpr int SLOTS = 16;
    const int lane = threadIdx.x & 63;
    const int node = blockIdx.x * 4 + (threadIdx.x >> 6);
    if (node >= n) return;
    const int l    = lane % LPR;
    const int slot = lane / LPR;
    const uint4* base = (const uint4*)tin + l;
    const int e0 = rp[node], e1 = rp[node + 1];
    float acc[8] = {0.f, 0.f, 0.f, 0.f, 0.f, 0.f, 0.f, 0.f};
    if (slot == 0) {
        float di = dinv[node];
        uint4 u = base[(size_t)node * LPR];
        hacc8(acc, u, di * di);
    }
    int p = e0 + slot;
    for (; p + SLOTS < e1; p += 2 * SLOTS) {
        long long r0 = __builtin_nontemporal_load(cn + p);
        long long r1 = __builtin_nontemporal_load(cn + p + SLOTS);
        uint4 u0 = base[(size_t)(unsigned)r0 * LPR];
        uint4 u1 = base[(size_t)(unsigned)r1 * LPR];
        hacc8(acc, u0, __int_as_float((int)(r0 >> 32)));
        hacc8(acc, u1, __int_as_float((int)(r1 >> 32)));
    }
    if (p < e1) {
        long long r0 = __builtin_nontemporal_load(cn + p);
        uint4 u0 = base[(size_t)(unsigned)r0 * LPR];
        hacc8(acc, u0, __int_as_float((int)(r0 >> 32)));
    }
    #pragma unroll
    for (int off = 32; off >= LPR; off >>= 1) {
        #pragma unroll
        for (int j = 0; j < 8; ++j) acc[j] += __shfl_xor(acc[j], off);
    }
    if (slot == 0) {
        float part = 0.f;
        #pragma unroll
        for (int j = 0; j < 8; ++j)
            part += fmaxf(acc[j] + ba2[l * 8 + j], 0.f) * A3[l * 8 + j];
        part += __shfl_xor(part, 1);
        part += __shfl_xor(part, 2);
        if (l == 0) wlin[node] = part;
    }
}

// F=1 aggregation for the attention scalar
__global__ void agg1_kernel(const float* __restrict__ tin, const float* __restrict__ bias,
        const float* __restrict__ dinv, const int* __restrict__ rp,
        const long long* __restrict__ cn, float* __restrict__ out, int n) {
    int i = blockIdx.x * 256 + threadIdx.x;
    if (i >= n) return;
    float di = dinv[i];
    float acc = di * di * tin[i];
    int e0 = rp[i], e1 = rp[i + 1];
    int p = e0;
    float a0 = 0.f, a1 = 0.f, a2 = 0.f, a3 = 0.f;
    for (; p + 3 < e1; p += 4) {
        long long r0 = __builtin_nontemporal_load(cn + p);
        long long r1 = __builtin_nontemporal_load(cn + p + 1);
        long long r2 = __builtin_nontemporal_load(cn + p + 2);
        long long r3 = __builtin_nontemporal_load(cn + p + 3);
        a0 += __int_as_float((int)(r0 >> 32)) * tin[(int)(unsigned)r0];
        a1 += __int_as_float((int)(r1 >> 32)) * tin[(int)(unsigned)r1];
        a2 += __int_as_float((int)(r2 >> 32)) * tin[(int)(unsigned)r2];
        a3 += __int_as_float((int)(r3 >> 32)) * tin[(int)(unsigned)r3];
    }
    for (; p < e1; ++p) {
        long long r0 = __builtin_nontemporal_load(cn + p);
        a0 += __int_as_float((int)(r0 >> 32)) * tin[(int)(unsigned)r0];
    }
    acc += a0 + a1 + a2 + a3 + bias[0];
    out[i] = acc > 0.f ? acc : 0.f;
}

// ---------------- fused per-graph softmax (max + exp + sum) ----------------

__global__ __launch_bounds__(256) void smexp_kernel(const float* __restrict__ w,
        const int* __restrict__ gstart, float* __restrict__ gsum,
        float* __restrict__ e) {
    const int g = blockIdx.x;
    const int a = gstart[g], b = gstart[g + 1];
    const int tid = threadIdx.x;
    __shared__ float red[4];
    float m = 0.f;                       // w >= 0 (post-relu)
    for (int i = a + tid; i < b; i += 256) m = fmaxf(m, w[i]);
    #pragma unroll
    for (int off = 32; off > 0; off >>= 1) m = fmaxf(m, __shfl_xor(m, off));
    if ((tid & 63) == 0) red[tid >> 6] = m;
    __syncthreads();
    m = fmaxf(fmaxf(red[0], red[1]), fmaxf(red[2], red[3]));
    float s = 0.f;
    for (int i = a + tid; i < b; i += 256) {
        float ex = expf(w[i] - m);
        e[i] = ex;
        s += ex;
    }
    #pragma unroll
    for (int off = 32; off > 0; off >>= 1) s += __shfl_xor(s, off);
    __syncthreads();
    if ((tid & 63) == 0) red[tid >> 6] = s;
    __syncthreads();
    if (tid == 0) gsum[g] = red[0] + red[1] + red[2] + red[3];
}

// ---------------- attention pooling ----------------

__global__ __launch_bounds__(128) void pool_kernel(const float* __restrict__ f3,
        const float* __restrict__ e, const float* __restrict__ gsum,
        const int* __restrict__ gstart, float* __restrict__ pooled) {
    constexpr int SPG = 64;
    const int g = blockIdx.x / SPG, s = blockIdx.x % SPG;
    const int a = gstart[g], bnd = gstart[g + 1];
    const int len = bnd - a;
    if (len <= 0) return;
    const int chunk = (len + SPG - 1) / SPG;
    const int lo = a + s * chunk;
    const int hi = min(lo + chunk, bnd);
    if (lo >= hi) return;
    const float inv = 1.f / (gsum[g] + 1e-16f);
    const int tid = threadIdx.x;
    const int lane4 = tid & 31;
    const int rs    = tid >> 5;
    f4 acc = {0.f, 0.f, 0.f, 0.f};
    for (int i = lo + rs; i < hi; i += 4) {
        float w = e[i] * inv;
        f4 v = *(const f4*)&f3[(size_t)i * FH + lane4 * 4];
        acc.x += w * v.x; acc.y += w * v.y;
        acc.z += w * v.z; acc.w += w * v.w;
    }
    acc.x += __shfl_xor(acc.x, 32);
    acc.y += __shfl_xor(acc.y, 32);
    acc.z += __shfl_xor(acc.z, 32);
    acc.w += __shfl_xor(acc.w, 32);
    __shared__ float sm[128];
    if (tid >= 64 && tid < 96) *(f4*)&sm[(tid - 64) * 4] = acc;
    __syncthreads();
    if (tid < 32) {
        f4 o = *(f4*)&sm[tid * 4];
        o.x += acc.x; o.y += acc.y; o.z += acc.z; o.w += acc.w;
        float* dst = &pooled[g * FH + tid * 4];
        atomicAdd(dst + 0, o.x);
        atomicAdd(dst + 1, o.y);
        atomicAdd(dst + 2, o.z);
        atomicAdd(dst + 3, o.w);
    }
}

// ---------------- MLP ----------------

__global__ __launch_bounds__(128) void mlp1_kernel(const float* __restrict__ pooled,
        const float* __restrict__ M1, const float* __restrict__ bm1,
        float* __restrict__ hidden) {
    __shared__ float pr[FH];
    int g = blockIdx.x, j = threadIdx.x;
    pr[j] = pooled[g * FH + j];
    __syncthreads();
    float acc = bm1[j];
    #pragma unroll 8
    for (int k = 0; k < FH; ++k) acc += pr[k] * M1[k * FH + j];
    hidden[g * FH + j] = acc > 0.f ? acc : 0.f;
}

__global__ __launch_bounds__(256) void mlp2_kernel(const float* __restrict__ hidden,
        const float* __restrict__ M2, const float* __restrict__ bm2,
        float* __restrict__ out) {
    __shared__ float hr[FH];
    int g = blockIdx.x, j = threadIdx.x;
    if (j < FH) hr[j] = hidden[g * FH + j];
    __syncthreads();
    float acc = bm2[j];
    #pragma unroll 8
    for (int k = 0; k < FH; ++k) acc += hr[k] * M2[k * DOUT + j];
    out[g * DOUT + j] = acc;
}

// ---------------------------------------------------------------------------

extern "C" void kernel_launch(void* const* d_in, const int* in_sizes, int n_in,
                              void* d_out, int out_size, void* d_ws, size_t ws_size,
                              hipStream_t stream) {
    const float* x   = (const float*)d_in[0];
    const int*   ei  = (const int*)d_in[1];
    const int*   batch = (const int*)d_in[2];
    const float* W1  = (const float*)d_in[3];
    const float* b1  = (const float*)d_in[4];
    const float* W2  = (const float*)d_in[5];
    const float* b2  = (const float*)d_in[6];
    const float* W3  = (const float*)d_in[7];
    const float* b3  = (const float*)d_in[8];
    const float* A1  = (const float*)d_in[9];
    const float* ba1 = (const float*)d_in[10];
    const float* A2  = (const float*)d_in[11];
    const float* ba2 = (const float*)d_in[12];
    const float* A3  = (const float*)d_in[13];
    const float* ba3 = (const float*)d_in[14];
    const float* M1  = (const float*)d_in[15];
    const float* bm1 = (const float*)d_in[16];
    const float* M2  = (const float*)d_in[17];
    const float* bm2 = (const float*)d_in[18];

    const int N = in_sizes[0] / DIN;
    const int E = in_sizes[1] / 2;
    const int G = out_size / DOUT;
    const int* src = ei;
    const int* dst = ei + E;
    float* out = (float*)d_out;

    // bucket shift: smallest s with ceil(N / 2^s) <= NBUK (=9 for N=50000)
    int shift = 9;
    while (((N + (1 << shift) - 1) >> shift) > NBUK) ++shift;
    const int nbuckets = (N + (1 << shift) - 1) >> shift;

    // workspace carve (aliased; see lifetime notes)
    char* p = (char*)d_ws;
    auto alloc = [&](size_t bytes) -> void* {
        void* r = (void*)p;
        p += (bytes + 255) & ~(size_t)255;
        return r;
    };
    float* dinv  = (float*)alloc((size_t)N * 4);
    int*   cnt   = (int*)alloc((size_t)N * 4);
    int*   rp    = (int*)alloc((size_t)(N + 1) * 4);
    long long* cn = (long long*)alloc((size_t)E * 8);
    float* SY    = (float*)alloc((size_t)N * FH * 4);   // Y, then f3
    float* SA    = (float*)alloc((size_t)N * FH * 4);   // entries, then f2
    __half* ST   = (__half*)alloc((size_t)N * FH * 2);  // t2, then t3 (fp16)
    char*  SX    = (char*)alloc((size_t)N * 256);       // xh (fp16)
    __half* u2   = (__half*)alloc((size_t)N * 32 * 2);
    float* wlin  = (float*)alloc((size_t)N * 4);
    float* wact  = (float*)alloc((size_t)N * 4);
    float* ebuf  = (float*)alloc((size_t)N * 4);
    float* gsum  = (float*)alloc((size_t)G * 4);
    int*   gstart= (int*)alloc((size_t)(G + 1) * 4);
    float* pooled= (float*)alloc((size_t)G * FH * 4);
    float* hidden= (float*)alloc((size_t)G * FH * 4);
    int*   bsum  = (int*)alloc(256 * 4);
    int*   boff  = (int*)alloc(256 * 4);
    int*   bcur  = (int*)alloc(NBUK * 4);
    _Float16* WT = (_Float16*)alloc((size_t)118784 * 2); // split-fp16 weights

    __half* xh = (__half*)SX;   // [N,128] fp16 (dead after Y-agg)
    unsigned long long* entries = (unsigned long long*)SA;  // NBUK*ECAP*8 = 16.8MB <= N*FH*4

    hipMemsetAsync(pooled, 0, (size_t)G * FH * 4, stream);

    const int nb = (N + 255) / 256;
    const int NB = (N + 511) / 512;

    wprep_kernel<<<232, 256, 0, stream>>>(W1, W2, W3, A1, A2, WT, bcur);
    // block-local sort + coalesced frontier appends (no global atomics on cnt)
    ebucket_kernel<<<(E + 2047) / 2048, 256, 0, stream>>>(src, dst, bcur, entries, E, shift);
    // degree histogram from bucketed entries (coalesced cnt writes)
    ecount_kernel<<<nbuckets, 512, 0, stream>>>(entries, bcur, cnt, N, shift);
    scan1_kernel<<<NB, 256, 0, stream>>>(cnt, bsum, dinv, N);
    scan2_kernel<<<1, 64, 0, stream>>>(bsum, boff, rp + N, NB);
    scan3_kernel<<<NB, 256, 0, stream>>>(cnt, boff, rp, N);
    gstart_kernel<<<1, 128, 0, stream>>>(batch, gstart, N, G);
    ecsr_kernel<<<nbuckets, 512, 0, stream>>>(entries, rp, dinv, cn, N, shift);

    const long n8 = (long)N * FH / 8;
    cvt16_kernel<<<(int)((n8 + 255) / 256), 256, 0, stream>>>(x, xh, n8);

    const int gb32 = (N + 31) / 32;
    const int agb  = (N + 3) / 4;

    // shared layer-1 aggregation: Y = A_hat x
    aggh_kernel<FH, false><<<agb, 256, 0, stream>>>(xh, nullptr, dinv, rp, cn, SY, N);

    // fused layer-1+2 linears: Y -> t2 (ST), u2
    fusedl1_kernel<<<gb32, 256, 0, stream>>>(SY, WT, b1, ba1, (__half*)ST, u2, N);

    // feature branch
    aggh_kernel<FH, true><<<agb, 256, 0, stream>>>(ST, b2, dinv, rp, cn, SA, N);          // f2
    t3gemm_kernel<<<gb32, 256, 0, stream>>>(SA, WT + 65536, WT + 81920, ST, N);           // t3
    aggh_kernel<FH, true><<<agb, 256, 0, stream>>>(ST, b3, dinv, rp, cn, SY, N);          // f3 -> SY

    // attention branch: a2-agg with fused a3 dot -> wlin, then scalar agg
    aggh32a_kernel<<<agb, 256, 0, stream>>>(u2, ba2, A3, dinv, rp, cn, wlin, N);
    agg1_kernel<<<nb, 256, 0, stream>>>(wlin, ba3, dinv, rp, cn, wact, N);

    // fused per-graph softmax + attention pooling
    smexp_kernel<<<G, 256, 0, stream>>>(wact, gstart, gsum, ebuf);
    pool_kernel<<<G * 64, 128, 0, stream>>>(SY, ebuf, gsum, gstart, pooled);

    // MLP
    mlp1_kernel<<<G, 128, 0, stream>>>(pooled, M1, bm1, hidden);
    mlp2_kernel<<<G, 256, 0, stream>>>(hidden, M2, bm2, out);
}

// Round 9
// 315.081 us; speedup vs baseline: 1.0096x; 1.0096x over previous
//
#include <hip/hip_runtime.h>
#include <hip/hip_fp16.h>
#include <math.h>

// ---------------------------------------------------------------------------
// GCN (3-layer feature + 3-layer attention) + segment softmax + attention
// pooling + MLP.
// R15: revert fusedl1 to R13 BM=64 (R14's BM=32 duplicated per-block weight
//     loads: 48us > 42.8us). Attention-branch gathers fused into the
//     feature gathers that walk the SAME edge list:
//       aggf2a2 = f2-agg(t2) + u2-agg + ba2/relu/A3 dot -> wlin
//       aggf3w  = f3-agg(t3) + wlin-agg -> wact
//     mlp1+mlp2 fused. Removes 3 dispatches + duplicate cn reads.
// ---------------------------------------------------------------------------

#define DIN 128
#define FH  128
#define DOUT 256
#define NBUK 128
#define SUBN 512
#define IMGCAP 16384
#define ECAP 16384

typedef float f4 __attribute__((ext_vector_type(4)));
typedef float f32x4 __attribute__((ext_vector_type(4)));
typedef _Float16 h8v __attribute__((ext_vector_type(8)));
typedef _Float16 h4v __attribute__((ext_vector_type(4)));

// ---------------- graph prep ----------------

// scan1 also produces dinv (rsqrt of degree+1) since it already loads cnt.
__global__ __launch_bounds__(256) void scan1_kernel(const int* __restrict__ cnt,
        int* __restrict__ bsum, float* __restrict__ dinv, int n) {
    __shared__ int sm[256];
    int tid = threadIdx.x;
    int base = blockIdx.x * 512;
    int a = (base + tid < n) ? cnt[base + tid] : 0;
    int b = (base + 256 + tid < n) ? cnt[base + 256 + tid] : 0;
    if (base + tid < n)       dinv[base + tid]       = rsqrtf((float)(a + 1));
    if (base + 256 + tid < n) dinv[base + 256 + tid] = rsqrtf((float)(b + 1));
    sm[tid] = a + b;
    __syncthreads();
    for (int off = 128; off > 0; off >>= 1) {
        if (tid < off) sm[tid] += sm[tid + off];
        __syncthreads();
    }
    if (tid == 0) bsum[blockIdx.x] = sm[0];
}

__global__ void scan2_kernel(const int* __restrict__ bsum, int* __restrict__ boff,
                             int* __restrict__ rpN, int nb) {
    if (threadIdx.x == 0) {
        int run = 0;
        for (int i = 0; i < nb; ++i) { boff[i] = run; run += bsum[i]; }
        *rpN = run;
    }
}

__global__ __launch_bounds__(256) void scan3_kernel(const int* __restrict__ cnt,
        const int* __restrict__ boff, int* __restrict__ rp, int n) {
    __shared__ int sm[256];
    int tid = threadIdx.x;
    int base = blockIdx.x * 512;
    int i0 = base + 2 * tid;
    int c0 = (i0 < n) ? cnt[i0] : 0;
    int c1 = (i0 + 1 < n) ? cnt[i0 + 1] : 0;
    int ps = c0 + c1;
    sm[tid] = ps;
    __syncthreads();
    for (int off = 1; off < 256; off <<= 1) {
        int v = (tid >= off) ? sm[tid - off] : 0;
        __syncthreads();
        sm[tid] += v;
        __syncthreads();
    }
    int excl = sm[tid] - ps + boff[blockIdx.x];
    if (i0 < n) rp[i0] = excl;
    if (i0 + 1 < n) rp[i0 + 1] = excl + c0;
}

// Pass A: block-local counting sort by bucket in LDS, then coalesced
// burst-out to per-bucket frontiers (bases at b*ECAP).
__global__ __launch_bounds__(256) void ebucket_kernel(const int* __restrict__ src,
        const int* __restrict__ dst, int* __restrict__ bcur,
        unsigned long long* __restrict__ entries, int E, int shift) {
    __shared__ int lcnt[NBUK], lscan[NBUK], lbase[NBUK], lcur[NBUK];
    __shared__ unsigned long long stage[2048];
    const int tid = threadIdx.x;
    const int e0 = blockIdx.x * 2048;
    if (tid < NBUK) { lcnt[tid] = 0; lcur[tid] = 0; }
    __syncthreads();
    int s_[8], d_[8];
    #pragma unroll
    for (int k = 0; k < 8; ++k) {
        int e = e0 + k * 256 + tid;
        if (e < E) {
            s_[k] = src[e];
            d_[k] = dst[e];
            atomicAdd(&lcnt[d_[k] >> shift], 1);
        } else {
            d_[k] = -1;
        }
    }
    __syncthreads();
    // exclusive scan over NBUK counters (Hillis-Steele, 128 lanes active)
    if (tid < NBUK) lscan[tid] = lcnt[tid];
    __syncthreads();
    for (int off = 1; off < NBUK; off <<= 1) {
        int v = 0;
        if (tid < NBUK && tid >= off) v = lscan[tid - off];
        __syncthreads();
        if (tid < NBUK) lscan[tid] += v;
        __syncthreads();
    }
    if (tid < NBUK) {
        lscan[tid] -= lcnt[tid];   // inclusive -> exclusive
        lbase[tid] = lcnt[tid] ? atomicAdd(&bcur[tid], lcnt[tid]) : 0;
    }
    __syncthreads();
    // scatter into LDS stage, sorted by bucket
    #pragma unroll
    for (int k = 0; k < 8; ++k) {
        if (d_[k] >= 0) {
            int b = d_[k] >> shift;
            int pos = lscan[b] + atomicAdd(&lcur[b], 1);
            stage[pos] = ((unsigned long long)(unsigned)d_[k] << 32) | (unsigned)s_[k];
        }
    }
    __syncthreads();
    // coalesced burst-out: LDS position i -> bucket via binary search
    const int total = min(2048, E - e0);
    for (int i = tid; i < total; i += 256) {
        int lo = 0, hi = NBUK - 1;
        while (lo < hi) {
            int mid = (lo + hi + 1) >> 1;
            if (lscan[mid] <= i) lo = mid; else hi = mid - 1;
        }
        int idx = lbase[lo] + (i - lscan[lo]);
        if (idx < (lo + 1) * ECAP)   // capacity guard (never hit: 91 sigma)
            entries[(size_t)idx] = stage[i];
    }
}

// Degree histogram from bucketed entries: one block per bucket, LDS
// histogram, coalesced cnt write.
__global__ __launch_bounds__(512) void ecount_kernel(
        const unsigned long long* __restrict__ entries,
        const int* __restrict__ bcur, int* __restrict__ cnt, int n, int shift) {
    __shared__ int hist[SUBN];
    const int b = blockIdx.x;
    const int n0 = b << shift;
    if (n0 >= n) return;
    const int n1 = min(n0 + SUBN, n);
    const int tid = threadIdx.x;
    hist[tid] = 0;
    __syncthreads();
    const size_t ebase = (size_t)b * ECAP;
    const int len = min(bcur[b] - b * ECAP, ECAP);
    for (int i = tid; i < len; i += 512)
        atomicAdd(&hist[(int)(entries[ebase + i] >> 32) - n0], 1);
    __syncthreads();
    if (n0 + tid < n1) cnt[n0 + tid] = hist[tid];
}

// Pass B: per-bucket counting sort fully in LDS, contiguous stream-out to cn.
__global__ __launch_bounds__(512) void ecsr_kernel(
        const unsigned long long* __restrict__ entries,
        const int* __restrict__ rp, const float* __restrict__ dinv,
        long long* __restrict__ cn, int n, int shift) {
    __shared__ long long img[IMGCAP];
    __shared__ int hist[SUBN];
    __shared__ int lcur[SUBN];
    __shared__ int sm[SUBN];
    __shared__ float dl[SUBN];
    const int b = blockIdx.x;
    const int n0 = b << shift;
    if (n0 >= n) return;
    const int n1 = min(n0 + (1 << shift), n);
    const int base = rp[n0];
    const int len  = rp[n1] - base;
    const size_t ebase = (size_t)b * ECAP;
    const int tid = threadIdx.x;
    hist[tid] = 0;
    lcur[tid] = 0;
    if (n0 + tid < n1) dl[tid] = dinv[n0 + tid];
    __syncthreads();
    for (int i = tid; i < len; i += 512)
        atomicAdd(&hist[(int)(entries[ebase + i] >> 32) - n0], 1);
    __syncthreads();
    int v = hist[tid];
    sm[tid] = v;
    __syncthreads();
    for (int off = 1; off < SUBN; off <<= 1) {
        int t = (tid >= off) ? sm[tid - off] : 0;
        __syncthreads();
        sm[tid] += t;
        __syncthreads();
    }
    hist[tid] = sm[tid] - v;
    __syncthreads();
    const bool fits = (len <= IMGCAP);
    for (int i = tid; i < len; i += 512) {
        unsigned long long e = entries[ebase + i];
        int d  = (int)(e >> 32) - n0;
        int sx = (int)(unsigned)(e & 0xffffffffu);
        int pos = hist[d] + atomicAdd(&lcur[d], 1);
        float w = dinv[sx] * dl[d];
        long long val = (long long)(unsigned)sx | ((long long)__float_as_int(w) << 32);
        if (fits) img[pos] = val;
        else      cn[base + pos] = val;
    }
    __syncthreads();
    if (fits)
        for (int i = tid; i < len; i += 512) cn[base + i] = img[i];
}

__global__ void gstart_kernel(const int* __restrict__ batch, int* __restrict__ gstart,
                              int n, int g) {
    int t = threadIdx.x;
    if (t > g) return;
    int lo = 0, hi = n;
    while (lo < hi) {
        int mid = (lo + hi) >> 1;
        if (batch[mid] < t) lo = mid + 1; else hi = mid;
    }
    gstart[t] = lo;
}

// fp32 -> fp16 convert (8 elems / thread)
__global__ void cvt16_kernel(const float* __restrict__ in, __half* __restrict__ outh,
                             long n8) {
    long i = (long)blockIdx.x * 256 + threadIdx.x;
    if (i >= n8) return;
    f4 a = ((const f4*)in)[2 * i];
    f4 b = ((const f4*)in)[2 * i + 1];
    __half2 h0 = __float22half2_rn(make_float2(a.x, a.y));
    __half2 h1 = __float22half2_rn(make_float2(a.z, a.w));
    __half2 h2 = __float22half2_rn(make_float2(b.x, b.y));
    __half2 h3 = __float22half2_rn(make_float2(b.z, b.w));
    uint4 st;
    st.x = *(unsigned*)&h0; st.y = *(unsigned*)&h1;
    st.z = *(unsigned*)&h2; st.w = *(unsigned*)&h3;
    ((uint4*)outh)[i] = st;
}

// ---------------- weight prep: split-fp16 transpose ----------------

__device__ __forceinline__ void wsplit(const float* __restrict__ W,
        _Float16* __restrict__ Th, _Float16* __restrict__ Tl,
        int fin, int fout, int i) {
    int r = i / fout, c = i % fout;
    float w = W[i];
    _Float16 h = (_Float16)w;
    Th[c * fin + r] = h;
    Tl[c * fin + r] = (_Float16)(w - (float)h);
}

// WT half-offsets: W1h=0 W1l=16384 W2h=32768 W2l=49152 W3h=65536 W3l=81920
//                  A1h=98304 A1l=106496 A2h=114688 A2l=116736  (total 118784)
__global__ __launch_bounds__(256) void wprep_kernel(const float* __restrict__ W1,
        const float* __restrict__ W2, const float* __restrict__ W3,
        const float* __restrict__ A1, const float* __restrict__ A2,
        _Float16* __restrict__ T, int* __restrict__ bcur) {
    int i = blockIdx.x * 256 + threadIdx.x;
    if (blockIdx.x == 0 && threadIdx.x < NBUK) bcur[threadIdx.x] = threadIdx.x * ECAP;
    if (i < 16384)       wsplit(W1, T,          T + 16384,  128, 128, i);
    else if (i < 32768)  wsplit(W2, T + 32768,  T + 49152,  128, 128, i - 16384);
    else if (i < 49152)  wsplit(W3, T + 65536,  T + 81920,  128, 128, i - 32768);
    else if (i < 57344)  wsplit(A1, T + 98304,  T + 106496, 128, 64,  i - 49152);
    else if (i < 59392)  wsplit(A2, T + 114688, T + 116736, 64,  32,  i - 57344);
}

// ---------------- fused layer-1 linears (split-fp16 MFMA), BM=64 ----------
// R13 structure (3 syncs, f1 aliases Y, accumulator lifetimes serialized)

__global__ __launch_bounds__(256) void fusedl1_kernel(const float* __restrict__ Y,
        const _Float16* __restrict__ T, const float* __restrict__ b1,
        const float* __restrict__ ba1, __half* __restrict__ t2,
        __half* __restrict__ u2, int n) {
    constexpr int LSTR  = 136;
    constexpr int LSTRB = 68;
    __shared__ _Float16 L1[64 * LSTR];     // Yh, then f1 high (alias)
    __shared__ _Float16 L2[64 * LSTR];     // Yl, then f1 low  (alias)
    __shared__ _Float16 Ah_[64 * LSTRB];   // a1 high
    __shared__ _Float16 Al_[64 * LSTRB];   // a1 low
    const int tid  = threadIdx.x;
    const int w    = tid >> 6;
    const int lane = tid & 63;
    const int bk   = (lane >> 4) * 8;
    const int cl   = lane & 15;
    const long row0 = (long)blockIdx.x * 64;

    // stage Y -> LDS, split fp32 -> fp16 h/l
    for (int i = tid; i < 64 * 32; i += 256) {
        int r = i >> 5, c4 = i & 31;
        long gr = row0 + r;
        float4 v = {0.f, 0.f, 0.f, 0.f};
        if (gr < n) v = *(const float4*)&Y[gr * 128 + c4 * 4];
        _Float16 h0 = (_Float16)v.x, h1 = (_Float16)v.y;
        _Float16 h2 = (_Float16)v.z, h3 = (_Float16)v.w;
        *(h4v*)&L1[r * LSTR + c4 * 4] = (h4v){h0, h1, h2, h3};
        *(h4v*)&L2[r * LSTR + c4 * 4] =
            (h4v){(_Float16)(v.x - (float)h0), (_Float16)(v.y - (float)h1),
                  (_Float16)(v.z - (float)h2), (_Float16)(v.w - (float)h3)};
    }
    __syncthreads();

    // ---- GEMM1b FIRST: accA = Y@A1, write a1 immediately (short reg life)
    {
        const _Float16* A1h = T + 98304;
        const _Float16* A1l = T + 106496;
        const int ca = w * 16 + cl;
        h8v A1hf[4], A1lf[4];
        #pragma unroll
        for (int kk = 0; kk < 4; ++kk) {
            A1hf[kk] = *(const h8v*)&A1h[ca * 128 + kk * 32 + bk];
            A1lf[kk] = *(const h8v*)&A1l[ca * 128 + kk * 32 + bk];
        }
        f32x4 accA[4];
        #pragma unroll
        for (int rt = 0; rt < 4; ++rt) accA[rt] = (f32x4){0.f,0.f,0.f,0.f};
        #pragma unroll
        for (int rt = 0; rt < 4; ++rt) {
            int r = rt * 16 + cl;
            #pragma unroll
            for (int kk = 0; kk < 4; ++kk) {
                h8v ah = *(const h8v*)&L1[r * LSTR + kk * 32 + bk];
                h8v al = *(const h8v*)&L2[r * LSTR + kk * 32 + bk];
                accA[rt] = __builtin_amdgcn_mfma_f32_16x16x32_f16(ah, A1hf[kk], accA[rt], 0, 0, 0);
                accA[rt] = __builtin_amdgcn_mfma_f32_16x16x32_f16(ah, A1lf[kk], accA[rt], 0, 0, 0);
                accA[rt] = __builtin_amdgcn_mfma_f32_16x16x32_f16(al, A1hf[kk], accA[rt], 0, 0, 0);
            }
        }
        float bv = ba1[ca];
        #pragma unroll
        for (int rt = 0; rt < 4; ++rt) {
            int rowb = rt * 16 + (lane >> 4) * 4;
            #pragma unroll
            for (int j = 0; j < 4; ++j) {
                float v = fmaxf(accA[rt][j] + bv, 0.f);
                _Float16 h = (_Float16)v;
                Ah_[(rowb + j) * LSTRB + ca] = h;
                Al_[(rowb + j) * LSTRB + ca] = (_Float16)(v - (float)h);
            }
        }
    }

    // ---- GEMM1a: accF = Y@W1 (wave w owns cols [w*32, w*32+32))
    f32x4 accF[4][2];
    {
        const _Float16* W1h = T;
        const _Float16* W1l = T + 16384;
        h8v Bh[2][4], Bl[2][4];
        #pragma unroll
        for (int ct = 0; ct < 2; ++ct) {
            int c = w * 32 + ct * 16 + cl;
            #pragma unroll
            for (int kk = 0; kk < 4; ++kk) {
                Bh[ct][kk] = *(const h8v*)&W1h[c * 128 + kk * 32 + bk];
                Bl[ct][kk] = *(const h8v*)&W1l[c * 128 + kk * 32 + bk];
            }
        }
        #pragma unroll
        for (int rt = 0; rt < 4; ++rt)
            #pragma unroll
            for (int ct = 0; ct < 2; ++ct) accF[rt][ct] = (f32x4){0.f,0.f,0.f,0.f};
        #pragma unroll
        for (int rt = 0; rt < 4; ++rt) {
            int r = rt * 16 + cl;
            #pragma unroll
            for (int kk = 0; kk < 4; ++kk) {
                h8v ah = *(const h8v*)&L1[r * LSTR + kk * 32 + bk];
                h8v al = *(const h8v*)&L2[r * LSTR + kk * 32 + bk];
                #pragma unroll
                for (int ct = 0; ct < 2; ++ct) {
                    accF[rt][ct] = __builtin_amdgcn_mfma_f32_16x16x32_f16(ah, Bh[ct][kk], accF[rt][ct], 0, 0, 0);
                    accF[rt][ct] = __builtin_amdgcn_mfma_f32_16x16x32_f16(ah, Bl[ct][kk], accF[rt][ct], 0, 0, 0);
                    accF[rt][ct] = __builtin_amdgcn_mfma_f32_16x16x32_f16(al, Bh[ct][kk], accF[rt][ct], 0, 0, 0);
                }
            }
        }
    }
    __syncthreads();   // all Y reads complete -> safe to overwrite L1/L2

    // ---- write f1 = relu(accF+b1) -> L1/L2 (alias)
    #pragma unroll
    for (int rt = 0; rt < 4; ++rt) {
        int rowb = rt * 16 + (lane >> 4) * 4;
        #pragma unroll
        for (int ct = 0; ct < 2; ++ct) {
            int col = w * 32 + ct * 16 + cl;
            float bv = b1[col];
            #pragma unroll
            for (int j = 0; j < 4; ++j) {
                float v = fmaxf(accF[rt][ct][j] + bv, 0.f);
                _Float16 h = (_Float16)v;
                L1[(rowb + j) * LSTR + col] = h;
                L2[(rowb + j) * LSTR + col] = (_Float16)(v - (float)h);
            }
        }
    }
    __syncthreads();

    // ---- GEMM2a: t2 = f1@W2 (fp16 out; wave w owns cols [w*32, w*32+32))
    {
        const _Float16* W2h = T + 32768;
        const _Float16* W2l = T + 49152;
        h8v Bh[2][4], Bl[2][4];
        #pragma unroll
        for (int ct = 0; ct < 2; ++ct) {
            int c = w * 32 + ct * 16 + cl;
            #pragma unroll
            for (int kk = 0; kk < 4; ++kk) {
                Bh[ct][kk] = *(const h8v*)&W2h[c * 128 + kk * 32 + bk];
                Bl[ct][kk] = *(const h8v*)&W2l[c * 128 + kk * 32 + bk];
            }
        }
        f32x4 acc[4][2];
        #pragma unroll
        for (int rt = 0; rt < 4; ++rt)
            #pragma unroll
            for (int ct = 0; ct < 2; ++ct) acc[rt][ct] = (f32x4){0.f,0.f,0.f,0.f};
        #pragma unroll
        for (int rt = 0; rt < 4; ++rt) {
            int r = rt * 16 + cl;
            #pragma unroll
            for (int kk = 0; kk < 4; ++kk) {
                h8v ah = *(const h8v*)&L1[r * LSTR + kk * 32 + bk];
                h8v al = *(const h8v*)&L2[r * LSTR + kk * 32 + bk];
                #pragma unroll
                for (int ct = 0; ct < 2; ++ct) {
                    acc[rt][ct] = __builtin_amdgcn_mfma_f32_16x16x32_f16(ah, Bh[ct][kk], acc[rt][ct], 0, 0, 0);
                    acc[rt][ct] = __builtin_amdgcn_mfma_f32_16x16x32_f16(ah, Bl[ct][kk], acc[rt][ct], 0, 0, 0);
                    acc[rt][ct] = __builtin_amdgcn_mfma_f32_16x16x32_f16(al, Bh[ct][kk], acc[rt][ct], 0, 0, 0);
                }
            }
        }
        #pragma unroll
        for (int rt = 0; rt < 4; ++rt) {
            long rbase = row0 + rt * 16 + (lane >> 4) * 4;
            #pragma unroll
            for (int ct = 0; ct < 2; ++ct) {
                int col = w * 32 + ct * 16 + cl;
                #pragma unroll
                for (int j = 0; j < 4; ++j) {
                    long r = rbase + j;
                    if (r < n) t2[r * 128 + col] = __float2half(acc[rt][ct][j]);
                }
            }
        }
    }

    // ---- GEMM2b: u2 = a1@A2 (fp16 out; wave w owns rows [w*16, w*16+16))
    {
        const _Float16* A2h = T + 114688;
        const _Float16* A2l = T + 116736;
        h8v Bh[2][2], Bl[2][2];
        #pragma unroll
        for (int ct = 0; ct < 2; ++ct) {
            int c = ct * 16 + cl;
            #pragma unroll
            for (int kk = 0; kk < 2; ++kk) {
                Bh[ct][kk] = *(const h8v*)&A2h[c * 64 + kk * 32 + bk];
                Bl[ct][kk] = *(const h8v*)&A2l[c * 64 + kk * 32 + bk];
            }
        }
        f32x4 acc[2];
        acc[0] = (f32x4){0.f,0.f,0.f,0.f};
        acc[1] = (f32x4){0.f,0.f,0.f,0.f};
        const int r = w * 16 + cl;
        #pragma unroll
        for (int kk = 0; kk < 2; ++kk) {
            h8v ah = *(const h8v*)&Ah_[r * LSTRB + kk * 32 + bk];
            h8v al = *(const h8v*)&Al_[r * LSTRB + kk * 32 + bk];
            #pragma unroll
            for (int ct = 0; ct < 2; ++ct) {
                acc[ct] = __builtin_amdgcn_mfma_f32_16x16x32_f16(ah, Bh[ct][kk], acc[ct], 0, 0, 0);
                acc[ct] = __builtin_amdgcn_mfma_f32_16x16x32_f16(ah, Bl[ct][kk], acc[ct], 0, 0, 0);
                acc[ct] = __builtin_amdgcn_mfma_f32_16x16x32_f16(al, Bh[ct][kk], acc[ct], 0, 0, 0);
            }
        }
        long rbase = row0 + w * 16 + (lane >> 4) * 4;
        #pragma unroll
        for (int ct = 0; ct < 2; ++ct) {
            int col = ct * 16 + cl;
            #pragma unroll
            for (int j = 0; j < 4; ++j) {
                long rr = rbase + j;
                if (rr < n) u2[rr * 32 + col] = __float2half(acc[ct][j]);
            }
        }
    }
}

// ---------------- MFMA dense linear (t3): C = A[n,128] @ W, BM=64 ----------
template<int FIN, int FOUT, int OMODE>
__global__ __launch_bounds__(256) void mgemm_kernel(const float* __restrict__ A,
        const _Float16* __restrict__ Wh, const _Float16* __restrict__ Wl,
        const float* __restrict__ bias, void* __restrict__ Cv, int n) {
    constexpr int NWC  = (FOUT / 16 < 4) ? FOUT / 16 : 4;
    constexpr int NWR  = 4 / NWC;
    constexpr int BM   = 64 * NWR;
    constexpr int CT   = FOUT / 16 / NWC;
    constexpr int KS   = FIN / 32;
    constexpr int LSTR = FIN + 8;
    __shared__ _Float16 Ahs[BM * LSTR];
    __shared__ _Float16 Als[BM * LSTR];

    const int tid  = threadIdx.x;
    const int w    = tid >> 6;
    const int lane = tid & 63;
    const long row0 = (long)blockIdx.x * BM;

    for (int i = tid; i < BM * (FIN / 4); i += 256) {
        int r  = i / (FIN / 4);
        int c4 = i % (FIN / 4);
        long gr = row0 + r;
        float4 v = {0.f, 0.f, 0.f, 0.f};
        if (gr < n) v = *(const float4*)&A[gr * FIN + c4 * 4];
        _Float16 h0 = (_Float16)v.x, h1 = (_Float16)v.y;
        _Float16 h2 = (_Float16)v.z, h3 = (_Float16)v.w;
        h4v hh = {h0, h1, h2, h3};
        h4v ll = {(_Float16)(v.x - (float)h0), (_Float16)(v.y - (float)h1),
                  (_Float16)(v.z - (float)h2), (_Float16)(v.w - (float)h3)};
        *(h4v*)&Ahs[r * LSTR + c4 * 4] = hh;
        *(h4v*)&Als[r * LSTR + c4 * 4] = ll;
    }

    const int wc = w % NWC;
    const int wr = w / NWC;
    const int colbase = wc * CT * 16;
    const int bk = (lane >> 4) * 8;
    h8v Bh[CT][KS], Bl[CT][KS];
    #pragma unroll
    for (int ct = 0; ct < CT; ++ct) {
        int c = colbase + ct * 16 + (lane & 15);
        #pragma unroll
        for (int kk = 0; kk < KS; ++kk) {
            Bh[ct][kk] = *(const h8v*)&Wh[(size_t)c * FIN + kk * 32 + bk];
            Bl[ct][kk] = *(const h8v*)&Wl[(size_t)c * FIN + kk * 32 + bk];
        }
    }

    __syncthreads();

    f32x4 acc[4][CT];
    #pragma unroll
    for (int rt = 0; rt < 4; ++rt)
        #pragma unroll
        for (int ct = 0; ct < CT; ++ct)
            acc[rt][ct] = (f32x4){0.f, 0.f, 0.f, 0.f};

    #pragma unroll
    for (int rt = 0; rt < 4; ++rt) {
        const int r = wr * 64 + rt * 16 + (lane & 15);
        #pragma unroll
        for (int kk = 0; kk < KS; ++kk) {
            h8v ah = *(const h8v*)&Ahs[r * LSTR + kk * 32 + bk];
            h8v al = *(const h8v*)&Als[r * LSTR + kk * 32 + bk];
            #pragma unroll
            for (int ct = 0; ct < CT; ++ct) {
                acc[rt][ct] = __builtin_amdgcn_mfma_f32_16x16x32_f16(ah, Bh[ct][kk], acc[rt][ct], 0, 0, 0);
                acc[rt][ct] = __builtin_amdgcn_mfma_f32_16x16x32_f16(ah, Bl[ct][kk], acc[rt][ct], 0, 0, 0);
                acc[rt][ct] = __builtin_amdgcn_mfma_f32_16x16x32_f16(al, Bh[ct][kk], acc[rt][ct], 0, 0, 0);
            }
        }
    }

    #pragma unroll
    for (int rt = 0; rt < 4; ++rt) {
        const long rbase = row0 + wr * 64 + rt * 16 + (lane >> 4) * 4;
        #pragma unroll
        for (int ct = 0; ct < CT; ++ct) {
            const int col = colbase + ct * 16 + (lane & 15);
            if (OMODE == 1) {
                const float bv = bias[col];
                #pragma unroll
                for (int j = 0; j < 4; ++j) {
                    long r = rbase + j;
                    if (r < n)
                        ((float*)Cv)[r * FOUT + col] = fmaxf(acc[rt][ct][j] + bv, 0.f);
                }
            } else {
                #pragma unroll
                for (int j = 0; j < 4; ++j) {
                    long r = rbase + j;
                    if (r < n)
                        ((__half*)Cv)[r * FOUT + col] = __float2half(acc[rt][ct][j]);
                }
            }
        }
    }
}

// ---------------- fp16-gather aggregation ----------------

__device__ __forceinline__ void hacc8(float acc[8], uint4 u, float w) {
    __half2 h; float2 f;
    h = *(__half2*)&u.x; f = __half22float2(h); acc[0] += w * f.x; acc[1] += w * f.y;
    h = *(__half2*)&u.y; f = __half22float2(h); acc[2] += w * f.x; acc[3] += w * f.y;
    h = *(__half2*)&u.z; f = __half22float2(h); acc[4] += w * f.x; acc[5] += w * f.y;
    h = *(__half2*)&u.w; f = __half22float2(h); acc[6] += w * f.x; acc[7] += w * f.y;
}

// plain F=128 aggregation (used for Y = A_hat x)
template<int F, bool BR>
__global__ __launch_bounds__(256) void aggh_kernel(const __half* __restrict__ tin,
        const float* __restrict__ bias, const float* __restrict__ dinv,
        const int* __restrict__ rp, const long long* __restrict__ cn,
        float* __restrict__ out, int n) {
    constexpr int LPR   = F / 8;
    constexpr int SLOTS = 64 / LPR;
    const int lane = threadIdx.x & 63;
    const int node = blockIdx.x * 4 + (threadIdx.x >> 6);
    if (node >= n) return;
    const int l    = lane % LPR;
    const int slot = lane / LPR;
    const uint4* base = (const uint4*)tin + l;
    const int e0 = rp[node], e1 = rp[node + 1];
    float acc[8] = {0.f, 0.f, 0.f, 0.f, 0.f, 0.f, 0.f, 0.f};
    if (slot == 0) {
        float di = dinv[node];
        uint4 u = base[(size_t)node * LPR];
        hacc8(acc, u, di * di);
    }
    int p = e0 + slot;
    for (; p + 3 * SLOTS < e1; p += 4 * SLOTS) {
        long long r0 = __builtin_nontemporal_load(cn + p);
        long long r1 = __builtin_nontemporal_load(cn + p + SLOTS);
        long long r2 = __builtin_nontemporal_load(cn + p + 2 * SLOTS);
        long long r3 = __builtin_nontemporal_load(cn + p + 3 * SLOTS);
        uint4 u0 = base[(size_t)(unsigned)r0 * LPR];
        uint4 u1 = base[(size_t)(unsigned)r1 * LPR];
        uint4 u2 = base[(size_t)(unsigned)r2 * LPR];
        uint4 u3 = base[(size_t)(unsigned)r3 * LPR];
        hacc8(acc, u0, __int_as_float((int)(r0 >> 32)));
        hacc8(acc, u1, __int_as_float((int)(r1 >> 32)));
        hacc8(acc, u2, __int_as_float((int)(r2 >> 32)));
        hacc8(acc, u3, __int_as_float((int)(r3 >> 32)));
    }
    for (; p + SLOTS < e1; p += 2 * SLOTS) {
        long long r0 = __builtin_nontemporal_load(cn + p);
        long long r1 = __builtin_nontemporal_load(cn + p + SLOTS);
        uint4 u0 = base[(size_t)(unsigned)r0 * LPR];
        uint4 u1 = base[(size_t)(unsigned)r1 * LPR];
        hacc8(acc, u0, __int_as_float((int)(r0 >> 32)));
        hacc8(acc, u1, __int_as_float((int)(r1 >> 32)));
    }
    if (p < e1) {
        long long r0 = __builtin_nontemporal_load(cn + p);
        uint4 u0 = base[(size_t)(unsigned)r0 * LPR];
        hacc8(acc, u0, __int_as_float((int)(r0 >> 32)));
    }
    #pragma unroll
    for (int off = 32; off >= LPR; off >>= 1) {
        #pragma unroll
        for (int j = 0; j < 8; ++j) acc[j] += __shfl_xor(acc[j], off);
    }
    if (slot == 0) {
        if (BR) {
            #pragma unroll
            for (int j = 0; j < 8; ++j)
                acc[j] = fmaxf(acc[j] + bias[l * 8 + j], 0.f);
        }
        f4 lo = {acc[0], acc[1], acc[2], acc[3]};
        f4 hi = {acc[4], acc[5], acc[6], acc[7]};
        float* o = out + (size_t)node * F + l * 8;
        __builtin_nontemporal_store(lo, (f4*)o);
        __builtin_nontemporal_store(hi, (f4*)(o + 4));
    }
}

// f2 = relu(agg(t2)+b2) AND wlin = relu(agg(u2)+ba2).A3, same edge walk.
__global__ __launch_bounds__(256) void aggf2a2_kernel(const __half* __restrict__ t2,
        const __half* __restrict__ u2, const float* __restrict__ b2,
        const float* __restrict__ ba2, const float* __restrict__ A3,
        const float* __restrict__ dinv, const int* __restrict__ rp,
        const long long* __restrict__ cn, float* __restrict__ f2,
        float* __restrict__ wlin, int n) {
    const int lane = threadIdx.x & 63;
    const int node = blockIdx.x * 4 + (threadIdx.x >> 6);
    if (node >= n) return;
    const int l    = lane & 15;
    const int slot = lane >> 4;
    const bool ul  = (l < 4);
    const uint4* base  = (const uint4*)t2 + l;
    const uint4* ubase = (const uint4*)u2 + l;
    const int e0 = rp[node], e1 = rp[node + 1];
    float acc[8]  = {0.f,0.f,0.f,0.f,0.f,0.f,0.f,0.f};
    float acc2[8] = {0.f,0.f,0.f,0.f,0.f,0.f,0.f,0.f};
    if (slot == 0) {
        float di = dinv[node];
        float dd = di * di;
        hacc8(acc, base[(size_t)node * 16], dd);
        if (ul) hacc8(acc2, ubase[(size_t)node * 4], dd);
    }
    int p = e0 + slot;
    for (; p + 12 < e1; p += 16) {
        long long r0 = __builtin_nontemporal_load(cn + p);
        long long r1 = __builtin_nontemporal_load(cn + p + 4);
        long long r2 = __builtin_nontemporal_load(cn + p + 8);
        long long r3 = __builtin_nontemporal_load(cn + p + 12);
        unsigned s0 = (unsigned)r0, s1 = (unsigned)r1, s2 = (unsigned)r2, s3 = (unsigned)r3;
        float w0 = __int_as_float((int)(r0 >> 32));
        float w1 = __int_as_float((int)(r1 >> 32));
        float w2 = __int_as_float((int)(r2 >> 32));
        float w3 = __int_as_float((int)(r3 >> 32));
        hacc8(acc, base[(size_t)s0 * 16], w0);
        hacc8(acc, base[(size_t)s1 * 16], w1);
        hacc8(acc, base[(size_t)s2 * 16], w2);
        hacc8(acc, base[(size_t)s3 * 16], w3);
        if (ul) {
            hacc8(acc2, ubase[(size_t)s0 * 4], w0);
            hacc8(acc2, ubase[(size_t)s1 * 4], w1);
            hacc8(acc2, ubase[(size_t)s2 * 4], w2);
            hacc8(acc2, ubase[(size_t)s3 * 4], w3);
        }
    }
    for (; p < e1; p += 4) {
        long long r0 = __builtin_nontemporal_load(cn + p);
        unsigned s0 = (unsigned)r0;
        float w0 = __int_as_float((int)(r0 >> 32));
        hacc8(acc, base[(size_t)s0 * 16], w0);
        if (ul) hacc8(acc2, ubase[(size_t)s0 * 4], w0);
    }
    #pragma unroll
    for (int off = 32; off >= 16; off >>= 1) {
        #pragma unroll
        for (int j = 0; j < 8; ++j) {
            acc[j]  += __shfl_xor(acc[j],  off);
            acc2[j] += __shfl_xor(acc2[j], off);
        }
    }
    if (slot == 0) {
        #pragma unroll
        for (int j = 0; j < 8; ++j)
            acc[j] = fmaxf(acc[j] + b2[l * 8 + j], 0.f);
        f4 lo = {acc[0], acc[1], acc[2], acc[3]};
        f4 hi = {acc[4], acc[5], acc[6], acc[7]};
        float* o = f2 + (size_t)node * FH + l * 8;
        __builtin_nontemporal_store(lo, (f4*)o);
        __builtin_nontemporal_store(hi, (f4*)(o + 4));
        // fused a3 dot
        float part = 0.f;
        if (ul) {
            #pragma unroll
            for (int j = 0; j < 8; ++j)
                part += fmaxf(acc2[j] + ba2[l * 8 + j], 0.f) * A3[l * 8 + j];
        }
        part += __shfl_xor(part, 1);
        part += __shfl_xor(part, 2);
        if (l == 0) wlin[node] = part;
    }
}

// f3 = relu(agg(t3)+b3) AND wact = relu(agg(wlin)+ba3), same edge walk.
__global__ __launch_bounds__(256) void aggf3w_kernel(const __half* __restrict__ t3,
        const float* __restrict__ wlin, const float* __restrict__ b3,
        const float* __restrict__ ba3, const float* __restrict__ dinv,
        const int* __restrict__ rp, const long long* __restrict__ cn,
        float* __restrict__ f3, float* __restrict__ wact, int n) {
    const int lane = threadIdx.x & 63;
    const int node = blockIdx.x * 4 + (threadIdx.x >> 6);
    if (node >= n) return;
    const int l    = lane & 15;
    const int slot = lane >> 4;
    const bool wl  = (l == 0);
    const uint4* base = (const uint4*)t3 + l;
    const int e0 = rp[node], e1 = rp[node + 1];
    float acc[8] = {0.f,0.f,0.f,0.f,0.f,0.f,0.f,0.f};
    float accw = 0.f;
    if (slot == 0) {
        float di = dinv[node];
        float dd = di * di;
        hacc8(acc, base[(size_t)node * 16], dd);
        if (wl) accw += dd * wlin[node];
    }
    int p = e0 + slot;
    for (; p + 12 < e1; p += 16) {
        long long r0 = __builtin_nontemporal_load(cn + p);
        long long r1 = __builtin_nontemporal_load(cn + p + 4);
        long long r2 = __builtin_nontemporal_load(cn + p + 8);
        long long r3 = __builtin_nontemporal_load(cn + p + 12);
        unsigned s0 = (unsigned)r0, s1 = (unsigned)r1, s2 = (unsigned)r2, s3 = (unsigned)r3;
        float w0 = __int_as_float((int)(r0 >> 32));
        float w1 = __int_as_float((int)(r1 >> 32));
        float w2 = __int_as_float((int)(r2 >> 32));
        float w3 = __int_as_float((int)(r3 >> 32));
        hacc8(acc, base[(size_t)s0 * 16], w0);
        hacc8(acc, base[(size_t)s1 * 16], w1);
        hacc8(acc, base[(size_t)s2 * 16], w2);
        hacc8(acc, base[(size_t)s3 * 16], w3);
        if (wl) {
            accw += w0 * wlin[s0] + w1 * wlin[s1];
            accw += w2 * wlin[s2] + w3 * wlin[s3];
        }
    }
    for (; p < e1; p += 4) {
        long long r0 = __builtin_nontemporal_load(cn + p);
        unsigned s0 = (unsigned)r0;
        float w0 = __int_as_float((int)(r0 >> 32));
        hacc8(acc, base[(size_t)s0 * 16], w0);
        if (wl) accw += w0 * wlin[s0];
    }
    #pragma unroll
    for (int off = 32; off >= 16; off >>= 1) {
        #pragma unroll
        for (int j = 0; j < 8; ++j) acc[j] += __shfl_xor(acc[j], off);
        accw += __shfl_xor(accw, off);
    }
    if (slot == 0) {
        #pragma unroll
        for (int j = 0; j < 8; ++j)
            acc[j] = fmaxf(acc[j] + b3[l * 8 + j], 0.f);
        f4 lo = {acc[0], acc[1], acc[2], acc[3]};
        f4 hi = {acc[4], acc[5], acc[6], acc[7]};
        float* o = f3 + (size_t)node * FH + l * 8;
        __builtin_nontemporal_store(lo, (f4*)o);
        __builtin_nontemporal_store(hi, (f4*)(o + 4));
        if (wl) {
            float v = accw + ba3[0];
            wact[node] = v > 0.f ? v : 0.f;
        }
    }
}

// ---------------- fused per-graph softmax (max + exp + sum) ----------------

__global__ __launch_bounds__(256) void smexp_kernel(const float* __restrict__ w,
        const int* __restrict__ gstart, float* __restrict__ gsum,
        float* __restrict__ e) {
    const int g = blockIdx.x;
    const int a = gstart[g], b = gstart[g + 1];
    const int tid = threadIdx.x;
    __shared__ float red[4];
    float m = 0.f;                       // w >= 0 (post-relu)
    for (int i = a + tid; i < b; i += 256) m = fmaxf(m, w[i]);
    #pragma unroll
    for (int off = 32; off > 0; off >>= 1) m = fmaxf(m, __shfl_xor(m, off));
    if ((tid & 63) == 0) red[tid >> 6] = m;
    __syncthreads();
    m = fmaxf(fmaxf(red[0], red[1]), fmaxf(red[2], red[3]));
    float s = 0.f;
    for (int i = a + tid; i < b; i += 256) {
        float ex = expf(w[i] - m);
        e[i] = ex;
        s += ex;
    }
    #pragma unroll
    for (int off = 32; off > 0; off >>= 1) s += __shfl_xor(s, off);
    __syncthreads();
    if ((tid & 63) == 0) red[tid >> 6] = s;
    __syncthreads();
    if (tid == 0) gsum[g] = red[0] + red[1] + red[2] + red[3];
}

// ---------------- attention pooling ----------------

__global__ __launch_bounds__(128) void pool_kernel(const float* __restrict__ f3,
        const float* __restrict__ e, const float* __restrict__ gsum,
        const int* __restrict__ gstart, float* __restrict__ pooled) {
    constexpr int SPG = 64;
    const int g = blockIdx.x / SPG, s = blockIdx.x % SPG;
    const int a = gstart[g], bnd = gstart[g + 1];
    const int len = bnd - a;
    if (len <= 0) return;
    const int chunk = (len + SPG - 1) / SPG;
    const int lo = a + s * chunk;
    const int hi = min(lo + chunk, bnd);
    if (lo >= hi) return;
    const float inv = 1.f / (gsum[g] + 1e-16f);
    const int tid = threadIdx.x;
    const int lane4 = tid & 31;
    const int rs    = tid >> 5;
    f4 acc = {0.f, 0.f, 0.f, 0.f};
    for (int i = lo + rs; i < hi; i += 4) {
        float w = e[i] * inv;
        f4 v = *(const f4*)&f3[(size_t)i * FH + lane4 * 4];
        acc.x += w * v.x; acc.y += w * v.y;
        acc.z += w * v.z; acc.w += w * v.w;
    }
    acc.x += __shfl_xor(acc.x, 32);
    acc.y += __shfl_xor(acc.y, 32);
    acc.z += __shfl_xor(acc.z, 32);
    acc.w += __shfl_xor(acc.w, 32);
    __shared__ float sm[128];
    if (tid >= 64 && tid < 96) *(f4*)&sm[(tid - 64) * 4] = acc;
    __syncthreads();
    if (tid < 32) {
        f4 o = *(f4*)&sm[tid * 4];
        o.x += acc.x; o.y += acc.y; o.z += acc.z; o.w += acc.w;
        float* dst = &pooled[g * FH + tid * 4];
        atomicAdd(dst + 0, o.x);
        atomicAdd(dst + 1, o.y);
        atomicAdd(dst + 2, o.z);
        atomicAdd(dst + 3, o.w);
    }
}

// ---------------- MLP (both layers fused; one block per graph) ----------------

__global__ __launch_bounds__(256) void mlp_kernel(const float* __restrict__ pooled,
        const float* __restrict__ M1, const float* __restrict__ bm1,
        const float* __restrict__ M2, const float* __restrict__ bm2,
        float* __restrict__ out) {
    __shared__ float pr[FH];
    __shared__ float hr[FH];
    int g = blockIdx.x, j = threadIdx.x;
    if (j < FH) pr[j] = pooled[g * FH + j];
    __syncthreads();
    if (j < FH) {
        float acc = bm1[j];
        #pragma unroll 8
        for (int k = 0; k < FH; ++k) acc += pr[k] * M1[k * FH + j];
        hr[j] = acc > 0.f ? acc : 0.f;
    }
    __syncthreads();
    float acc = bm2[j];
    #pragma unroll 8
    for (int k = 0; k < FH; ++k) acc += hr[k] * M2[k * DOUT + j];
    out[g * DOUT + j] = acc;
}

// ---------------------------------------------------------------------------

extern "C" void kernel_launch(void* const* d_in, const int* in_sizes, int n_in,
                              void* d_out, int out_size, void* d_ws, size_t ws_size,
                              hipStream_t stream) {
    const float* x   = (const float*)d_in[0];
    const int*   ei  = (const int*)d_in[1];
    const int*   batch = (const int*)d_in[2];
    const float* W1  = (const float*)d_in[3];
    const float* b1  = (const float*)d_in[4];
    const float* W2  = (const float*)d_in[5];
    const float* b2  = (const float*)d_in[6];
    const float* W3  = (const float*)d_in[7];
    const float* b3  = (const float*)d_in[8];
    const float* A1  = (const float*)d_in[9];
    const float* ba1 = (const float*)d_in[10];
    const float* A2  = (const float*)d_in[11];
    const float* ba2 = (const float*)d_in[12];
    const float* A3  = (const float*)d_in[13];
    const float* ba3 = (const float*)d_in[14];
    const float* M1  = (const float*)d_in[15];
    const float* bm1 = (const float*)d_in[16];
    const float* M2  = (const float*)d_in[17];
    const float* bm2 = (const float*)d_in[18];

    const int N = in_sizes[0] / DIN;
    const int E = in_sizes[1] / 2;
    const int G = out_size / DOUT;
    const int* src = ei;
    const int* dst = ei + E;
    float* out = (float*)d_out;

    // bucket shift: smallest s with ceil(N / 2^s) <= NBUK (=9 for N=50000)
    int shift = 9;
    while (((N + (1 << shift) - 1) >> shift) > NBUK) ++shift;
    const int nbuckets = (N + (1 << shift) - 1) >> shift;

    // workspace carve (aliased; see lifetime notes)
    char* p = (char*)d_ws;
    auto alloc = [&](size_t bytes) -> void* {
        void* r = (void*)p;
        p += (bytes + 255) & ~(size_t)255;
        return r;
    };
    float* dinv  = (float*)alloc((size_t)N * 4);
    int*   cnt   = (int*)alloc((size_t)N * 4);
    int*   rp    = (int*)alloc((size_t)(N + 1) * 4);
    long long* cn = (long long*)alloc((size_t)E * 8);
    float* SY    = (float*)alloc((size_t)N * FH * 4);   // Y, then f3
    float* SA    = (float*)alloc((size_t)N * FH * 4);   // entries, then f2
    __half* ST   = (__half*)alloc((size_t)N * FH * 2);  // t2, then t3 (fp16)
    char*  SX    = (char*)alloc((size_t)N * 256);       // xh (fp16)
    __half* u2   = (__half*)alloc((size_t)N * 32 * 2);
    float* wlin  = (float*)alloc((size_t)N * 4);
    float* wact  = (float*)alloc((size_t)N * 4);
    float* ebuf  = (float*)alloc((size_t)N * 4);
    float* gsum  = (float*)alloc((size_t)G * 4);
    int*   gstart= (int*)alloc((size_t)(G + 1) * 4);
    float* pooled= (float*)alloc((size_t)G * FH * 4);
    int*   bsum  = (int*)alloc(256 * 4);
    int*   boff  = (int*)alloc(256 * 4);
    int*   bcur  = (int*)alloc(NBUK * 4);
    _Float16* WT = (_Float16*)alloc((size_t)118784 * 2); // split-fp16 weights

    __half* xh = (__half*)SX;   // [N,128] fp16 (dead after Y-agg)
    unsigned long long* entries = (unsigned long long*)SA;  // NBUK*ECAP*8 = 16.8MB <= N*FH*4

    hipMemsetAsync(pooled, 0, (size_t)G * FH * 4, stream);

    const int NB = (N + 511) / 512;

    wprep_kernel<<<232, 256, 0, stream>>>(W1, W2, W3, A1, A2, WT, bcur);
    ebucket_kernel<<<(E + 2047) / 2048, 256, 0, stream>>>(src, dst, bcur, entries, E, shift);
    ecount_kernel<<<nbuckets, 512, 0, stream>>>(entries, bcur, cnt, N, shift);
    scan1_kernel<<<NB, 256, 0, stream>>>(cnt, bsum, dinv, N);
    scan2_kernel<<<1, 64, 0, stream>>>(bsum, boff, rp + N, NB);
    scan3_kernel<<<NB, 256, 0, stream>>>(cnt, boff, rp, N);
    gstart_kernel<<<1, 128, 0, stream>>>(batch, gstart, N, G);
    ecsr_kernel<<<nbuckets, 512, 0, stream>>>(entries, rp, dinv, cn, N, shift);

    const long n8 = (long)N * FH / 8;
    cvt16_kernel<<<(int)((n8 + 255) / 256), 256, 0, stream>>>(x, xh, n8);

    const int gb64 = (N + 63) / 64;
    const int agb  = (N + 3) / 4;

    // shared layer-1 aggregation: Y = A_hat x
    aggh_kernel<FH, false><<<agb, 256, 0, stream>>>(xh, nullptr, dinv, rp, cn, SY, N);

    // fused layer-1+2 linears: Y -> t2 (ST), u2
    fusedl1_kernel<<<gb64, 256, 0, stream>>>(SY, WT, b1, ba1, (__half*)ST, u2, N);

    // f2-agg + a2-agg + a3 dot (one edge walk) -> f2 (SA), wlin
    aggf2a2_kernel<<<agb, 256, 0, stream>>>((__half*)ST, u2, b2, ba2, A3,
                                            dinv, rp, cn, SA, wlin, N);
    // t3 = f2@W3
    mgemm_kernel<FH, FH, 2><<<gb64, 256, 0, stream>>>(SA, WT + 65536, WT + 81920, nullptr, ST, N);
    // f3-agg + wlin-agg (one edge walk) -> f3 (SY), wact
    aggf3w_kernel<<<agb, 256, 0, stream>>>((__half*)ST, wlin, b3, ba3,
                                           dinv, rp, cn, SY, wact, N);

    // fused per-graph softmax + attention pooling
    smexp_kernel<<<G, 256, 0, stream>>>(wact, gstart, gsum, ebuf);
    pool_kernel<<<G * 64, 128, 0, stream>>>(SY, ebuf, gsum, gstart, pooled);

    // MLP (fused)
    mlp_kernel<<<G, 256, 0, stream>>>(pooled, M1, bm1, M2, bm2, out);
}

// Round 10
// 308.909 us; speedup vs baseline: 1.0298x; 1.0200x over previous
//
#include <hip/hip_runtime.h>
#include <hip/hip_fp16.h>
#include <math.h>

// ---------------------------------------------------------------------------
// GCN (3-layer feature + 3-layer attention) + segment softmax + attention
// pooling + MLP.
// R16: revert R15's gather fusion (L2 thrash: t2's 12.8MB stream evicted the
//     previously-L2-resident 3.2MB u2 table -> +42MB FETCH, 74us vs 50us
//     separate). Back to R13's proven set; keep only the fused MLP launch.
//     Lesson: never merge gathers over disjoint tables whose combined
//     working set exceeds per-XCD L2.
// ---------------------------------------------------------------------------

#define DIN 128
#define FH  128
#define DOUT 256
#define NBUK 128
#define SUBN 512
#define IMGCAP 16384
#define ECAP 16384

typedef float f4 __attribute__((ext_vector_type(4)));
typedef float f32x4 __attribute__((ext_vector_type(4)));
typedef _Float16 h8v __attribute__((ext_vector_type(8)));
typedef _Float16 h4v __attribute__((ext_vector_type(4)));

// ---------------- graph prep ----------------

// scan1 also produces dinv (rsqrt of degree+1) since it already loads cnt.
__global__ __launch_bounds__(256) void scan1_kernel(const int* __restrict__ cnt,
        int* __restrict__ bsum, float* __restrict__ dinv, int n) {
    __shared__ int sm[256];
    int tid = threadIdx.x;
    int base = blockIdx.x * 512;
    int a = (base + tid < n) ? cnt[base + tid] : 0;
    int b = (base + 256 + tid < n) ? cnt[base + 256 + tid] : 0;
    if (base + tid < n)       dinv[base + tid]       = rsqrtf((float)(a + 1));
    if (base + 256 + tid < n) dinv[base + 256 + tid] = rsqrtf((float)(b + 1));
    sm[tid] = a + b;
    __syncthreads();
    for (int off = 128; off > 0; off >>= 1) {
        if (tid < off) sm[tid] += sm[tid + off];
        __syncthreads();
    }
    if (tid == 0) bsum[blockIdx.x] = sm[0];
}

__global__ void scan2_kernel(const int* __restrict__ bsum, int* __restrict__ boff,
                             int* __restrict__ rpN, int nb) {
    if (threadIdx.x == 0) {
        int run = 0;
        for (int i = 0; i < nb; ++i) { boff[i] = run; run += bsum[i]; }
        *rpN = run;
    }
}

__global__ __launch_bounds__(256) void scan3_kernel(const int* __restrict__ cnt,
        const int* __restrict__ boff, int* __restrict__ rp, int n) {
    __shared__ int sm[256];
    int tid = threadIdx.x;
    int base = blockIdx.x * 512;
    int i0 = base + 2 * tid;
    int c0 = (i0 < n) ? cnt[i0] : 0;
    int c1 = (i0 + 1 < n) ? cnt[i0 + 1] : 0;
    int ps = c0 + c1;
    sm[tid] = ps;
    __syncthreads();
    for (int off = 1; off < 256; off <<= 1) {
        int v = (tid >= off) ? sm[tid - off] : 0;
        __syncthreads();
        sm[tid] += v;
        __syncthreads();
    }
    int excl = sm[tid] - ps + boff[blockIdx.x];
    if (i0 < n) rp[i0] = excl;
    if (i0 + 1 < n) rp[i0 + 1] = excl + c0;
}

// Pass A: block-local counting sort by bucket in LDS, then coalesced
// burst-out to per-bucket frontiers (bases at b*ECAP).
__global__ __launch_bounds__(256) void ebucket_kernel(const int* __restrict__ src,
        const int* __restrict__ dst, int* __restrict__ bcur,
        unsigned long long* __restrict__ entries, int E, int shift) {
    __shared__ int lcnt[NBUK], lscan[NBUK], lbase[NBUK], lcur[NBUK];
    __shared__ unsigned long long stage[2048];
    const int tid = threadIdx.x;
    const int e0 = blockIdx.x * 2048;
    if (tid < NBUK) { lcnt[tid] = 0; lcur[tid] = 0; }
    __syncthreads();
    int s_[8], d_[8];
    #pragma unroll
    for (int k = 0; k < 8; ++k) {
        int e = e0 + k * 256 + tid;
        if (e < E) {
            s_[k] = src[e];
            d_[k] = dst[e];
            atomicAdd(&lcnt[d_[k] >> shift], 1);
        } else {
            d_[k] = -1;
        }
    }
    __syncthreads();
    // exclusive scan over NBUK counters (Hillis-Steele, 128 lanes active)
    if (tid < NBUK) lscan[tid] = lcnt[tid];
    __syncthreads();
    for (int off = 1; off < NBUK; off <<= 1) {
        int v = 0;
        if (tid < NBUK && tid >= off) v = lscan[tid - off];
        __syncthreads();
        if (tid < NBUK) lscan[tid] += v;
        __syncthreads();
    }
    if (tid < NBUK) {
        lscan[tid] -= lcnt[tid];   // inclusive -> exclusive
        lbase[tid] = lcnt[tid] ? atomicAdd(&bcur[tid], lcnt[tid]) : 0;
    }
    __syncthreads();
    // scatter into LDS stage, sorted by bucket
    #pragma unroll
    for (int k = 0; k < 8; ++k) {
        if (d_[k] >= 0) {
            int b = d_[k] >> shift;
            int pos = lscan[b] + atomicAdd(&lcur[b], 1);
            stage[pos] = ((unsigned long long)(unsigned)d_[k] << 32) | (unsigned)s_[k];
        }
    }
    __syncthreads();
    // coalesced burst-out: LDS position i -> bucket via binary search
    const int total = min(2048, E - e0);
    for (int i = tid; i < total; i += 256) {
        int lo = 0, hi = NBUK - 1;
        while (lo < hi) {
            int mid = (lo + hi + 1) >> 1;
            if (lscan[mid] <= i) lo = mid; else hi = mid - 1;
        }
        int idx = lbase[lo] + (i - lscan[lo]);
        if (idx < (lo + 1) * ECAP)   // capacity guard (never hit: 91 sigma)
            entries[(size_t)idx] = stage[i];
    }
}

// Degree histogram from bucketed entries: one block per bucket, LDS
// histogram, coalesced cnt write.
__global__ __launch_bounds__(512) void ecount_kernel(
        const unsigned long long* __restrict__ entries,
        const int* __restrict__ bcur, int* __restrict__ cnt, int n, int shift) {
    __shared__ int hist[SUBN];
    const int b = blockIdx.x;
    const int n0 = b << shift;
    if (n0 >= n) return;
    const int n1 = min(n0 + SUBN, n);
    const int tid = threadIdx.x;
    hist[tid] = 0;
    __syncthreads();
    const size_t ebase = (size_t)b * ECAP;
    const int len = min(bcur[b] - b * ECAP, ECAP);
    for (int i = tid; i < len; i += 512)
        atomicAdd(&hist[(int)(entries[ebase + i] >> 32) - n0], 1);
    __syncthreads();
    if (n0 + tid < n1) cnt[n0 + tid] = hist[tid];
}

// Pass B: per-bucket counting sort fully in LDS, contiguous stream-out to cn.
__global__ __launch_bounds__(512) void ecsr_kernel(
        const unsigned long long* __restrict__ entries,
        const int* __restrict__ rp, const float* __restrict__ dinv,
        long long* __restrict__ cn, int n, int shift) {
    __shared__ long long img[IMGCAP];
    __shared__ int hist[SUBN];
    __shared__ int lcur[SUBN];
    __shared__ int sm[SUBN];
    __shared__ float dl[SUBN];
    const int b = blockIdx.x;
    const int n0 = b << shift;
    if (n0 >= n) return;
    const int n1 = min(n0 + (1 << shift), n);
    const int base = rp[n0];
    const int len  = rp[n1] - base;
    const size_t ebase = (size_t)b * ECAP;
    const int tid = threadIdx.x;
    hist[tid] = 0;
    lcur[tid] = 0;
    if (n0 + tid < n1) dl[tid] = dinv[n0 + tid];
    __syncthreads();
    for (int i = tid; i < len; i += 512)
        atomicAdd(&hist[(int)(entries[ebase + i] >> 32) - n0], 1);
    __syncthreads();
    int v = hist[tid];
    sm[tid] = v;
    __syncthreads();
    for (int off = 1; off < SUBN; off <<= 1) {
        int t = (tid >= off) ? sm[tid - off] : 0;
        __syncthreads();
        sm[tid] += t;
        __syncthreads();
    }
    hist[tid] = sm[tid] - v;
    __syncthreads();
    const bool fits = (len <= IMGCAP);
    for (int i = tid; i < len; i += 512) {
        unsigned long long e = entries[ebase + i];
        int d  = (int)(e >> 32) - n0;
        int sx = (int)(unsigned)(e & 0xffffffffu);
        int pos = hist[d] + atomicAdd(&lcur[d], 1);
        float w = dinv[sx] * dl[d];
        long long val = (long long)(unsigned)sx | ((long long)__float_as_int(w) << 32);
        if (fits) img[pos] = val;
        else      cn[base + pos] = val;
    }
    __syncthreads();
    if (fits)
        for (int i = tid; i < len; i += 512) cn[base + i] = img[i];
}

__global__ void gstart_kernel(const int* __restrict__ batch, int* __restrict__ gstart,
                              int n, int g) {
    int t = threadIdx.x;
    if (t > g) return;
    int lo = 0, hi = n;
    while (lo < hi) {
        int mid = (lo + hi) >> 1;
        if (batch[mid] < t) lo = mid + 1; else hi = mid;
    }
    gstart[t] = lo;
}

// fp32 -> fp16 convert (8 elems / thread)
__global__ void cvt16_kernel(const float* __restrict__ in, __half* __restrict__ outh,
                             long n8) {
    long i = (long)blockIdx.x * 256 + threadIdx.x;
    if (i >= n8) return;
    f4 a = ((const f4*)in)[2 * i];
    f4 b = ((const f4*)in)[2 * i + 1];
    __half2 h0 = __float22half2_rn(make_float2(a.x, a.y));
    __half2 h1 = __float22half2_rn(make_float2(a.z, a.w));
    __half2 h2 = __float22half2_rn(make_float2(b.x, b.y));
    __half2 h3 = __float22half2_rn(make_float2(b.z, b.w));
    uint4 st;
    st.x = *(unsigned*)&h0; st.y = *(unsigned*)&h1;
    st.z = *(unsigned*)&h2; st.w = *(unsigned*)&h3;
    ((uint4*)outh)[i] = st;
}

// ---------------- weight prep: split-fp16 transpose ----------------

__device__ __forceinline__ void wsplit(const float* __restrict__ W,
        _Float16* __restrict__ Th, _Float16* __restrict__ Tl,
        int fin, int fout, int i) {
    int r = i / fout, c = i % fout;
    float w = W[i];
    _Float16 h = (_Float16)w;
    Th[c * fin + r] = h;
    Tl[c * fin + r] = (_Float16)(w - (float)h);
}

// WT half-offsets: W1h=0 W1l=16384 W2h=32768 W2l=49152 W3h=65536 W3l=81920
//                  A1h=98304 A1l=106496 A2h=114688 A2l=116736  (total 118784)
__global__ __launch_bounds__(256) void wprep_kernel(const float* __restrict__ W1,
        const float* __restrict__ W2, const float* __restrict__ W3,
        const float* __restrict__ A1, const float* __restrict__ A2,
        _Float16* __restrict__ T, int* __restrict__ bcur) {
    int i = blockIdx.x * 256 + threadIdx.x;
    if (blockIdx.x == 0 && threadIdx.x < NBUK) bcur[threadIdx.x] = threadIdx.x * ECAP;
    if (i < 16384)       wsplit(W1, T,          T + 16384,  128, 128, i);
    else if (i < 32768)  wsplit(W2, T + 32768,  T + 49152,  128, 128, i - 16384);
    else if (i < 49152)  wsplit(W3, T + 65536,  T + 81920,  128, 128, i - 32768);
    else if (i < 57344)  wsplit(A1, T + 98304,  T + 106496, 128, 64,  i - 49152);
    else if (i < 59392)  wsplit(A2, T + 114688, T + 116736, 64,  32,  i - 57344);
}

// ---------------- fused layer-1 linears (split-fp16 MFMA), BM=64 ----------
// R13 structure (3 syncs, f1 aliases Y, accumulator lifetimes serialized)

__global__ __launch_bounds__(256) void fusedl1_kernel(const float* __restrict__ Y,
        const _Float16* __restrict__ T, const float* __restrict__ b1,
        const float* __restrict__ ba1, __half* __restrict__ t2,
        __half* __restrict__ u2, int n) {
    constexpr int LSTR  = 136;
    constexpr int LSTRB = 68;
    __shared__ _Float16 L1[64 * LSTR];     // Yh, then f1 high (alias)
    __shared__ _Float16 L2[64 * LSTR];     // Yl, then f1 low  (alias)
    __shared__ _Float16 Ah_[64 * LSTRB];   // a1 high
    __shared__ _Float16 Al_[64 * LSTRB];   // a1 low
    const int tid  = threadIdx.x;
    const int w    = tid >> 6;
    const int lane = tid & 63;
    const int bk   = (lane >> 4) * 8;
    const int cl   = lane & 15;
    const long row0 = (long)blockIdx.x * 64;

    // stage Y -> LDS, split fp32 -> fp16 h/l
    for (int i = tid; i < 64 * 32; i += 256) {
        int r = i >> 5, c4 = i & 31;
        long gr = row0 + r;
        float4 v = {0.f, 0.f, 0.f, 0.f};
        if (gr < n) v = *(const float4*)&Y[gr * 128 + c4 * 4];
        _Float16 h0 = (_Float16)v.x, h1 = (_Float16)v.y;
        _Float16 h2 = (_Float16)v.z, h3 = (_Float16)v.w;
        *(h4v*)&L1[r * LSTR + c4 * 4] = (h4v){h0, h1, h2, h3};
        *(h4v*)&L2[r * LSTR + c4 * 4] =
            (h4v){(_Float16)(v.x - (float)h0), (_Float16)(v.y - (float)h1),
                  (_Float16)(v.z - (float)h2), (_Float16)(v.w - (float)h3)};
    }
    __syncthreads();

    // ---- GEMM1b FIRST: accA = Y@A1, write a1 immediately (short reg life)
    {
        const _Float16* A1h = T + 98304;
        const _Float16* A1l = T + 106496;
        const int ca = w * 16 + cl;
        h8v A1hf[4], A1lf[4];
        #pragma unroll
        for (int kk = 0; kk < 4; ++kk) {
            A1hf[kk] = *(const h8v*)&A1h[ca * 128 + kk * 32 + bk];
            A1lf[kk] = *(const h8v*)&A1l[ca * 128 + kk * 32 + bk];
        }
        f32x4 accA[4];
        #pragma unroll
        for (int rt = 0; rt < 4; ++rt) accA[rt] = (f32x4){0.f,0.f,0.f,0.f};
        #pragma unroll
        for (int rt = 0; rt < 4; ++rt) {
            int r = rt * 16 + cl;
            #pragma unroll
            for (int kk = 0; kk < 4; ++kk) {
                h8v ah = *(const h8v*)&L1[r * LSTR + kk * 32 + bk];
                h8v al = *(const h8v*)&L2[r * LSTR + kk * 32 + bk];
                accA[rt] = __builtin_amdgcn_mfma_f32_16x16x32_f16(ah, A1hf[kk], accA[rt], 0, 0, 0);
                accA[rt] = __builtin_amdgcn_mfma_f32_16x16x32_f16(ah, A1lf[kk], accA[rt], 0, 0, 0);
                accA[rt] = __builtin_amdgcn_mfma_f32_16x16x32_f16(al, A1hf[kk], accA[rt], 0, 0, 0);
            }
        }
        float bv = ba1[ca];
        #pragma unroll
        for (int rt = 0; rt < 4; ++rt) {
            int rowb = rt * 16 + (lane >> 4) * 4;
            #pragma unroll
            for (int j = 0; j < 4; ++j) {
                float v = fmaxf(accA[rt][j] + bv, 0.f);
                _Float16 h = (_Float16)v;
                Ah_[(rowb + j) * LSTRB + ca] = h;
                Al_[(rowb + j) * LSTRB + ca] = (_Float16)(v - (float)h);
            }
        }
    }

    // ---- GEMM1a: accF = Y@W1 (wave w owns cols [w*32, w*32+32))
    f32x4 accF[4][2];
    {
        const _Float16* W1h = T;
        const _Float16* W1l = T + 16384;
        h8v Bh[2][4], Bl[2][4];
        #pragma unroll
        for (int ct = 0; ct < 2; ++ct) {
            int c = w * 32 + ct * 16 + cl;
            #pragma unroll
            for (int kk = 0; kk < 4; ++kk) {
                Bh[ct][kk] = *(const h8v*)&W1h[c * 128 + kk * 32 + bk];
                Bl[ct][kk] = *(const h8v*)&W1l[c * 128 + kk * 32 + bk];
            }
        }
        #pragma unroll
        for (int rt = 0; rt < 4; ++rt)
            #pragma unroll
            for (int ct = 0; ct < 2; ++ct) accF[rt][ct] = (f32x4){0.f,0.f,0.f,0.f};
        #pragma unroll
        for (int rt = 0; rt < 4; ++rt) {
            int r = rt * 16 + cl;
            #pragma unroll
            for (int kk = 0; kk < 4; ++kk) {
                h8v ah = *(const h8v*)&L1[r * LSTR + kk * 32 + bk];
                h8v al = *(const h8v*)&L2[r * LSTR + kk * 32 + bk];
                #pragma unroll
                for (int ct = 0; ct < 2; ++ct) {
                    accF[rt][ct] = __builtin_amdgcn_mfma_f32_16x16x32_f16(ah, Bh[ct][kk], accF[rt][ct], 0, 0, 0);
                    accF[rt][ct] = __builtin_amdgcn_mfma_f32_16x16x32_f16(ah, Bl[ct][kk], accF[rt][ct], 0, 0, 0);
                    accF[rt][ct] = __builtin_amdgcn_mfma_f32_16x16x32_f16(al, Bh[ct][kk], accF[rt][ct], 0, 0, 0);
                }
            }
        }
    }
    __syncthreads();   // all Y reads complete -> safe to overwrite L1/L2

    // ---- write f1 = relu(accF+b1) -> L1/L2 (alias)
    #pragma unroll
    for (int rt = 0; rt < 4; ++rt) {
        int rowb = rt * 16 + (lane >> 4) * 4;
        #pragma unroll
        for (int ct = 0; ct < 2; ++ct) {
            int col = w * 32 + ct * 16 + cl;
            float bv = b1[col];
            #pragma unroll
            for (int j = 0; j < 4; ++j) {
                float v = fmaxf(accF[rt][ct][j] + bv, 0.f);
                _Float16 h = (_Float16)v;
                L1[(rowb + j) * LSTR + col] = h;
                L2[(rowb + j) * LSTR + col] = (_Float16)(v - (float)h);
            }
        }
    }
    __syncthreads();

    // ---- GEMM2a: t2 = f1@W2 (fp16 out; wave w owns cols [w*32, w*32+32))
    {
        const _Float16* W2h = T + 32768;
        const _Float16* W2l = T + 49152;
        h8v Bh[2][4], Bl[2][4];
        #pragma unroll
        for (int ct = 0; ct < 2; ++ct) {
            int c = w * 32 + ct * 16 + cl;
            #pragma unroll
            for (int kk = 0; kk < 4; ++kk) {
                Bh[ct][kk] = *(const h8v*)&W2h[c * 128 + kk * 32 + bk];
                Bl[ct][kk] = *(const h8v*)&W2l[c * 128 + kk * 32 + bk];
            }
        }
        f32x4 acc[4][2];
        #pragma unroll
        for (int rt = 0; rt < 4; ++rt)
            #pragma unroll
            for (int ct = 0; ct < 2; ++ct) acc[rt][ct] = (f32x4){0.f,0.f,0.f,0.f};
        #pragma unroll
        for (int rt = 0; rt < 4; ++rt) {
            int r = rt * 16 + cl;
            #pragma unroll
            for (int kk = 0; kk < 4; ++kk) {
                h8v ah = *(const h8v*)&L1[r * LSTR + kk * 32 + bk];
                h8v al = *(const h8v*)&L2[r * LSTR + kk * 32 + bk];
                #pragma unroll
                for (int ct = 0; ct < 2; ++ct) {
                    acc[rt][ct] = __builtin_amdgcn_mfma_f32_16x16x32_f16(ah, Bh[ct][kk], acc[rt][ct], 0, 0, 0);
                    acc[rt][ct] = __builtin_amdgcn_mfma_f32_16x16x32_f16(ah, Bl[ct][kk], acc[rt][ct], 0, 0, 0);
                    acc[rt][ct] = __builtin_amdgcn_mfma_f32_16x16x32_f16(al, Bh[ct][kk], acc[rt][ct], 0, 0, 0);
                }
            }
        }
        #pragma unroll
        for (int rt = 0; rt < 4; ++rt) {
            long rbase = row0 + rt * 16 + (lane >> 4) * 4;
            #pragma unroll
            for (int ct = 0; ct < 2; ++ct) {
                int col = w * 32 + ct * 16 + cl;
                #pragma unroll
                for (int j = 0; j < 4; ++j) {
                    long r = rbase + j;
                    if (r < n) t2[r * 128 + col] = __float2half(acc[rt][ct][j]);
                }
            }
        }
    }

    // ---- GEMM2b: u2 = a1@A2 (fp16 out; wave w owns rows [w*16, w*16+16))
    {
        const _Float16* A2h = T + 114688;
        const _Float16* A2l = T + 116736;
        h8v Bh[2][2], Bl[2][2];
        #pragma unroll
        for (int ct = 0; ct < 2; ++ct) {
            int c = ct * 16 + cl;
            #pragma unroll
            for (int kk = 0; kk < 2; ++kk) {
                Bh[ct][kk] = *(const h8v*)&A2h[c * 64 + kk * 32 + bk];
                Bl[ct][kk] = *(const h8v*)&A2l[c * 64 + kk * 32 + bk];
            }
        }
        f32x4 acc[2];
        acc[0] = (f32x4){0.f,0.f,0.f,0.f};
        acc[1] = (f32x4){0.f,0.f,0.f,0.f};
        const int r = w * 16 + cl;
        #pragma unroll
        for (int kk = 0; kk < 2; ++kk) {
            h8v ah = *(const h8v*)&Ah_[r * LSTRB + kk * 32 + bk];
            h8v al = *(const h8v*)&Al_[r * LSTRB + kk * 32 + bk];
            #pragma unroll
            for (int ct = 0; ct < 2; ++ct) {
                acc[ct] = __builtin_amdgcn_mfma_f32_16x16x32_f16(ah, Bh[ct][kk], acc[ct], 0, 0, 0);
                acc[ct] = __builtin_amdgcn_mfma_f32_16x16x32_f16(ah, Bl[ct][kk], acc[ct], 0, 0, 0);
                acc[ct] = __builtin_amdgcn_mfma_f32_16x16x32_f16(al, Bh[ct][kk], acc[ct], 0, 0, 0);
            }
        }
        long rbase = row0 + w * 16 + (lane >> 4) * 4;
        #pragma unroll
        for (int ct = 0; ct < 2; ++ct) {
            int col = ct * 16 + cl;
            #pragma unroll
            for (int j = 0; j < 4; ++j) {
                long rr = rbase + j;
                if (rr < n) u2[rr * 32 + col] = __float2half(acc[ct][j]);
            }
        }
    }
}

// ---------------- MFMA dense linear (t3): C = A[n,128] @ W, BM=64 ----------
template<int FIN, int FOUT, int OMODE>
__global__ __launch_bounds__(256) void mgemm_kernel(const float* __restrict__ A,
        const _Float16* __restrict__ Wh, const _Float16* __restrict__ Wl,
        const float* __restrict__ bias, void* __restrict__ Cv, int n) {
    constexpr int NWC  = (FOUT / 16 < 4) ? FOUT / 16 : 4;
    constexpr int NWR  = 4 / NWC;
    constexpr int BM   = 64 * NWR;
    constexpr int CT   = FOUT / 16 / NWC;
    constexpr int KS   = FIN / 32;
    constexpr int LSTR = FIN + 8;
    __shared__ _Float16 Ahs[BM * LSTR];
    __shared__ _Float16 Als[BM * LSTR];

    const int tid  = threadIdx.x;
    const int w    = tid >> 6;
    const int lane = tid & 63;
    const long row0 = (long)blockIdx.x * BM;

    for (int i = tid; i < BM * (FIN / 4); i += 256) {
        int r  = i / (FIN / 4);
        int c4 = i % (FIN / 4);
        long gr = row0 + r;
        float4 v = {0.f, 0.f, 0.f, 0.f};
        if (gr < n) v = *(const float4*)&A[gr * FIN + c4 * 4];
        _Float16 h0 = (_Float16)v.x, h1 = (_Float16)v.y;
        _Float16 h2 = (_Float16)v.z, h3 = (_Float16)v.w;
        h4v hh = {h0, h1, h2, h3};
        h4v ll = {(_Float16)(v.x - (float)h0), (_Float16)(v.y - (float)h1),
                  (_Float16)(v.z - (float)h2), (_Float16)(v.w - (float)h3)};
        *(h4v*)&Ahs[r * LSTR + c4 * 4] = hh;
        *(h4v*)&Als[r * LSTR + c4 * 4] = ll;
    }

    const int wc = w % NWC;
    const int wr = w / NWC;
    const int colbase = wc * CT * 16;
    const int bk = (lane >> 4) * 8;
    h8v Bh[CT][KS], Bl[CT][KS];
    #pragma unroll
    for (int ct = 0; ct < CT; ++ct) {
        int c = colbase + ct * 16 + (lane & 15);
        #pragma unroll
        for (int kk = 0; kk < KS; ++kk) {
            Bh[ct][kk] = *(const h8v*)&Wh[(size_t)c * FIN + kk * 32 + bk];
            Bl[ct][kk] = *(const h8v*)&Wl[(size_t)c * FIN + kk * 32 + bk];
        }
    }

    __syncthreads();

    f32x4 acc[4][CT];
    #pragma unroll
    for (int rt = 0; rt < 4; ++rt)
        #pragma unroll
        for (int ct = 0; ct < CT; ++ct)
            acc[rt][ct] = (f32x4){0.f, 0.f, 0.f, 0.f};

    #pragma unroll
    for (int rt = 0; rt < 4; ++rt) {
        const int r = wr * 64 + rt * 16 + (lane & 15);
        #pragma unroll
        for (int kk = 0; kk < KS; ++kk) {
            h8v ah = *(const h8v*)&Ahs[r * LSTR + kk * 32 + bk];
            h8v al = *(const h8v*)&Als[r * LSTR + kk * 32 + bk];
            #pragma unroll
            for (int ct = 0; ct < CT; ++ct) {
                acc[rt][ct] = __builtin_amdgcn_mfma_f32_16x16x32_f16(ah, Bh[ct][kk], acc[rt][ct], 0, 0, 0);
                acc[rt][ct] = __builtin_amdgcn_mfma_f32_16x16x32_f16(ah, Bl[ct][kk], acc[rt][ct], 0, 0, 0);
                acc[rt][ct] = __builtin_amdgcn_mfma_f32_16x16x32_f16(al, Bh[ct][kk], acc[rt][ct], 0, 0, 0);
            }
        }
    }

    #pragma unroll
    for (int rt = 0; rt < 4; ++rt) {
        const long rbase = row0 + wr * 64 + rt * 16 + (lane >> 4) * 4;
        #pragma unroll
        for (int ct = 0; ct < CT; ++ct) {
            const int col = colbase + ct * 16 + (lane & 15);
            if (OMODE == 1) {
                const float bv = bias[col];
                #pragma unroll
                for (int j = 0; j < 4; ++j) {
                    long r = rbase + j;
                    if (r < n)
                        ((float*)Cv)[r * FOUT + col] = fmaxf(acc[rt][ct][j] + bv, 0.f);
                }
            } else {
                #pragma unroll
                for (int j = 0; j < 4; ++j) {
                    long r = rbase + j;
                    if (r < n)
                        ((__half*)Cv)[r * FOUT + col] = __float2half(acc[rt][ct][j]);
                }
            }
        }
    }
}

// ---------------- fp16-gather aggregation ----------------

__device__ __forceinline__ void hacc8(float acc[8], uint4 u, float w) {
    __half2 h; float2 f;
    h = *(__half2*)&u.x; f = __half22float2(h); acc[0] += w * f.x; acc[1] += w * f.y;
    h = *(__half2*)&u.y; f = __half22float2(h); acc[2] += w * f.x; acc[3] += w * f.y;
    h = *(__half2*)&u.z; f = __half22float2(h); acc[4] += w * f.x; acc[5] += w * f.y;
    h = *(__half2*)&u.w; f = __half22float2(h); acc[6] += w * f.x; acc[7] += w * f.y;
}

template<int F, bool BR>
__global__ __launch_bounds__(256) void aggh_kernel(const __half* __restrict__ tin,
        const float* __restrict__ bias, const float* __restrict__ dinv,
        const int* __restrict__ rp, const long long* __restrict__ cn,
        float* __restrict__ out, int n) {
    constexpr int LPR   = F / 8;
    constexpr int SLOTS = 64 / LPR;
    const int lane = threadIdx.x & 63;
    const int node = blockIdx.x * 4 + (threadIdx.x >> 6);
    if (node >= n) return;
    const int l    = lane % LPR;
    const int slot = lane / LPR;
    const uint4* base = (const uint4*)tin + l;
    const int e0 = rp[node], e1 = rp[node + 1];
    float acc[8] = {0.f, 0.f, 0.f, 0.f, 0.f, 0.f, 0.f, 0.f};
    if (slot == 0) {
        float di = dinv[node];
        uint4 u = base[(size_t)node * LPR];
        hacc8(acc, u, di * di);
    }
    int p = e0 + slot;
    for (; p + 3 * SLOTS < e1; p += 4 * SLOTS) {
        long long r0 = __builtin_nontemporal_load(cn + p);
        long long r1 = __builtin_nontemporal_load(cn + p + SLOTS);
        long long r2 = __builtin_nontemporal_load(cn + p + 2 * SLOTS);
        long long r3 = __builtin_nontemporal_load(cn + p + 3 * SLOTS);
        uint4 u0 = base[(size_t)(unsigned)r0 * LPR];
        uint4 u1 = base[(size_t)(unsigned)r1 * LPR];
        uint4 u2 = base[(size_t)(unsigned)r2 * LPR];
        uint4 u3 = base[(size_t)(unsigned)r3 * LPR];
        hacc8(acc, u0, __int_as_float((int)(r0 >> 32)));
        hacc8(acc, u1, __int_as_float((int)(r1 >> 32)));
        hacc8(acc, u2, __int_as_float((int)(r2 >> 32)));
        hacc8(acc, u3, __int_as_float((int)(r3 >> 32)));
    }
    for (; p + SLOTS < e1; p += 2 * SLOTS) {
        long long r0 = __builtin_nontemporal_load(cn + p);
        long long r1 = __builtin_nontemporal_load(cn + p + SLOTS);
        uint4 u0 = base[(size_t)(unsigned)r0 * LPR];
        uint4 u1 = base[(size_t)(unsigned)r1 * LPR];
        hacc8(acc, u0, __int_as_float((int)(r0 >> 32)));
        hacc8(acc, u1, __int_as_float((int)(r1 >> 32)));
    }
    if (p < e1) {
        long long r0 = __builtin_nontemporal_load(cn + p);
        uint4 u0 = base[(size_t)(unsigned)r0 * LPR];
        hacc8(acc, u0, __int_as_float((int)(r0 >> 32)));
    }
    #pragma unroll
    for (int off = 32; off >= LPR; off >>= 1) {
        #pragma unroll
        for (int j = 0; j < 8; ++j) acc[j] += __shfl_xor(acc[j], off);
    }
    if (slot == 0) {
        if (BR) {
            #pragma unroll
            for (int j = 0; j < 8; ++j)
                acc[j] = fmaxf(acc[j] + bias[l * 8 + j], 0.f);
        }
        f4 lo = {acc[0], acc[1], acc[2], acc[3]};
        f4 hi = {acc[4], acc[5], acc[6], acc[7]};
        float* o = out + (size_t)node * F + l * 8;
        __builtin_nontemporal_store(lo, (f4*)o);
        __builtin_nontemporal_store(hi, (f4*)(o + 4));
    }
}

// a2-aggregation (F=32) with fused a3 dot: wlin[node] = relu(agg+ba2) . A3
__global__ __launch_bounds__(256) void aggh32a_kernel(const __half* __restrict__ tin,
        const float* __restrict__ ba2, const float* __restrict__ A3,
        const float* __restrict__ dinv, const int* __restrict__ rp,
        const long long* __restrict__ cn, float* __restrict__ wlin, int n) {
    constexpr int LPR   = 4;
    constexpr int SLOTS = 16;
    const int lane = threadIdx.x & 63;
    const int node = blockIdx.x * 4 + (threadIdx.x >> 6);
    if (node >= n) return;
    const int l    = lane % LPR;
    const int slot = lane / LPR;
    const uint4* base = (const uint4*)tin + l;
    const int e0 = rp[node], e1 = rp[node + 1];
    float acc[8] = {0.f, 0.f, 0.f, 0.f, 0.f, 0.f, 0.f, 0.f};
    if (slot == 0) {
        float di = dinv[node];
        uint4 u = base[(size_t)node * LPR];
        hacc8(acc, u, di * di);
    }
    int p = e0 + slot;
    for (; p + SLOTS < e1; p += 2 * SLOTS) {
        long long r0 = __builtin_nontemporal_load(cn + p);
        long long r1 = __builtin_nontemporal_load(cn + p + SLOTS);
        uint4 u0 = base[(size_t)(unsigned)r0 * LPR];
        uint4 u1 = base[(size_t)(unsigned)r1 * LPR];
        hacc8(acc, u0, __int_as_float((int)(r0 >> 32)));
        hacc8(acc, u1, __int_as_float((int)(r1 >> 32)));
    }
    if (p < e1) {
        long long r0 = __builtin_nontemporal_load(cn + p);
        uint4 u0 = base[(size_t)(unsigned)r0 * LPR];
        hacc8(acc, u0, __int_as_float((int)(r0 >> 32)));
    }
    #pragma unroll
    for (int off = 32; off >= LPR; off >>= 1) {
        #pragma unroll
        for (int j = 0; j < 8; ++j) acc[j] += __shfl_xor(acc[j], off);
    }
    if (slot == 0) {
        float part = 0.f;
        #pragma unroll
        for (int j = 0; j < 8; ++j)
            part += fmaxf(acc[j] + ba2[l * 8 + j], 0.f) * A3[l * 8 + j];
        part += __shfl_xor(part, 1);
        part += __shfl_xor(part, 2);
        if (l == 0) wlin[node] = part;
    }
}

// F=1 aggregation for the attention scalar
__global__ void agg1_kernel(const float* __restrict__ tin, const float* __restrict__ bias,
        const float* __restrict__ dinv, const int* __restrict__ rp,
        const long long* __restrict__ cn, float* __restrict__ out, int n) {
    int i = blockIdx.x * 256 + threadIdx.x;
    if (i >= n) return;
    float di = dinv[i];
    float acc = di * di * tin[i];
    int e0 = rp[i], e1 = rp[i + 1];
    int p = e0;
    float a0 = 0.f, a1 = 0.f, a2 = 0.f, a3 = 0.f;
    for (; p + 3 < e1; p += 4) {
        long long r0 = __builtin_nontemporal_load(cn + p);
        long long r1 = __builtin_nontemporal_load(cn + p + 1);
        long long r2 = __builtin_nontemporal_load(cn + p + 2);
        long long r3 = __builtin_nontemporal_load(cn + p + 3);
        a0 += __int_as_float((int)(r0 >> 32)) * tin[(int)(unsigned)r0];
        a1 += __int_as_float((int)(r1 >> 32)) * tin[(int)(unsigned)r1];
        a2 += __int_as_float((int)(r2 >> 32)) * tin[(int)(unsigned)r2];
        a3 += __int_as_float((int)(r3 >> 32)) * tin[(int)(unsigned)r3];
    }
    for (; p < e1; ++p) {
        long long r0 = __builtin_nontemporal_load(cn + p);
        a0 += __int_as_float((int)(r0 >> 32)) * tin[(int)(unsigned)r0];
    }
    acc += a0 + a1 + a2 + a3 + bias[0];
    out[i] = acc > 0.f ? acc : 0.f;
}

// ---------------- fused per-graph softmax (max + exp + sum) ----------------

__global__ __launch_bounds__(256) void smexp_kernel(const float* __restrict__ w,
        const int* __restrict__ gstart, float* __restrict__ gsum,
        float* __restrict__ e) {
    const int g = blockIdx.x;
    const int a = gstart[g], b = gstart[g + 1];
    const int tid = threadIdx.x;
    __shared__ float red[4];
    float m = 0.f;                       // w >= 0 (post-relu)
    for (int i = a + tid; i < b; i += 256) m = fmaxf(m, w[i]);
    #pragma unroll
    for (int off = 32; off > 0; off >>= 1) m = fmaxf(m, __shfl_xor(m, off));
    if ((tid & 63) == 0) red[tid >> 6] = m;
    __syncthreads();
    m = fmaxf(fmaxf(red[0], red[1]), fmaxf(red[2], red[3]));
    float s = 0.f;
    for (int i = a + tid; i < b; i += 256) {
        float ex = expf(w[i] - m);
        e[i] = ex;
        s += ex;
    }
    #pragma unroll
    for (int off = 32; off > 0; off >>= 1) s += __shfl_xor(s, off);
    __syncthreads();
    if ((tid & 63) == 0) red[tid >> 6] = s;
    __syncthreads();
    if (tid == 0) gsum[g] = red[0] + red[1] + red[2] + red[3];
}

// ---------------- attention pooling ----------------

__global__ __launch_bounds__(128) void pool_kernel(const float* __restrict__ f3,
        const float* __restrict__ e, const float* __restrict__ gsum,
        const int* __restrict__ gstart, float* __restrict__ pooled) {
    constexpr int SPG = 64;
    const int g = blockIdx.x / SPG, s = blockIdx.x % SPG;
    const int a = gstart[g], bnd = gstart[g + 1];
    const int len = bnd - a;
    if (len <= 0) return;
    const int chunk = (len + SPG - 1) / SPG;
    const int lo = a + s * chunk;
    const int hi = min(lo + chunk, bnd);
    if (lo >= hi) return;
    const float inv = 1.f / (gsum[g] + 1e-16f);
    const int tid = threadIdx.x;
    const int lane4 = tid & 31;
    const int rs    = tid >> 5;
    f4 acc = {0.f, 0.f, 0.f, 0.f};
    for (int i = lo + rs; i < hi; i += 4) {
        float w = e[i] * inv;
        f4 v = *(const f4*)&f3[(size_t)i * FH + lane4 * 4];
        acc.x += w * v.x; acc.y += w * v.y;
        acc.z += w * v.z; acc.w += w * v.w;
    }
    acc.x += __shfl_xor(acc.x, 32);
    acc.y += __shfl_xor(acc.y, 32);
    acc.z += __shfl_xor(acc.z, 32);
    acc.w += __shfl_xor(acc.w, 32);
    __shared__ float sm[128];
    if (tid >= 64 && tid < 96) *(f4*)&sm[(tid - 64) * 4] = acc;
    __syncthreads();
    if (tid < 32) {
        f4 o = *(f4*)&sm[tid * 4];
        o.x += acc.x; o.y += acc.y; o.z += acc.z; o.w += acc.w;
        float* dst = &pooled[g * FH + tid * 4];
        atomicAdd(dst + 0, o.x);
        atomicAdd(dst + 1, o.y);
        atomicAdd(dst + 2, o.z);
        atomicAdd(dst + 3, o.w);
    }
}

// ---------------- MLP (both layers fused; one block per graph) ----------------

__global__ __launch_bounds__(256) void mlp_kernel(const float* __restrict__ pooled,
        const float* __restrict__ M1, const float* __restrict__ bm1,
        const float* __restrict__ M2, const float* __restrict__ bm2,
        float* __restrict__ out) {
    __shared__ float pr[FH];
    __shared__ float hr[FH];
    int g = blockIdx.x, j = threadIdx.x;
    if (j < FH) pr[j] = pooled[g * FH + j];
    __syncthreads();
    if (j < FH) {
        float acc = bm1[j];
        #pragma unroll 8
        for (int k = 0; k < FH; ++k) acc += pr[k] * M1[k * FH + j];
        hr[j] = acc > 0.f ? acc : 0.f;
    }
    __syncthreads();
    float acc = bm2[j];
    #pragma unroll 8
    for (int k = 0; k < FH; ++k) acc += hr[k] * M2[k * DOUT + j];
    out[g * DOUT + j] = acc;
}

// ---------------------------------------------------------------------------

extern "C" void kernel_launch(void* const* d_in, const int* in_sizes, int n_in,
                              void* d_out, int out_size, void* d_ws, size_t ws_size,
                              hipStream_t stream) {
    const float* x   = (const float*)d_in[0];
    const int*   ei  = (const int*)d_in[1];
    const int*   batch = (const int*)d_in[2];
    const float* W1  = (const float*)d_in[3];
    const float* b1  = (const float*)d_in[4];
    const float* W2  = (const float*)d_in[5];
    const float* b2  = (const float*)d_in[6];
    const float* W3  = (const float*)d_in[7];
    const float* b3  = (const float*)d_in[8];
    const float* A1  = (const float*)d_in[9];
    const float* ba1 = (const float*)d_in[10];
    const float* A2  = (const float*)d_in[11];
    const float* ba2 = (const float*)d_in[12];
    const float* A3  = (const float*)d_in[13];
    const float* ba3 = (const float*)d_in[14];
    const float* M1  = (const float*)d_in[15];
    const float* bm1 = (const float*)d_in[16];
    const float* M2  = (const float*)d_in[17];
    const float* bm2 = (const float*)d_in[18];

    const int N = in_sizes[0] / DIN;
    const int E = in_sizes[1] / 2;
    const int G = out_size / DOUT;
    const int* src = ei;
    const int* dst = ei + E;
    float* out = (float*)d_out;

    // bucket shift: smallest s with ceil(N / 2^s) <= NBUK (=9 for N=50000)
    int shift = 9;
    while (((N + (1 << shift) - 1) >> shift) > NBUK) ++shift;
    const int nbuckets = (N + (1 << shift) - 1) >> shift;

    // workspace carve (aliased; see lifetime notes)
    char* p = (char*)d_ws;
    auto alloc = [&](size_t bytes) -> void* {
        void* r = (void*)p;
        p += (bytes + 255) & ~(size_t)255;
        return r;
    };
    float* dinv  = (float*)alloc((size_t)N * 4);
    int*   cnt   = (int*)alloc((size_t)N * 4);
    int*   rp    = (int*)alloc((size_t)(N + 1) * 4);
    long long* cn = (long long*)alloc((size_t)E * 8);
    float* SY    = (float*)alloc((size_t)N * FH * 4);   // Y, then f3
    float* SA    = (float*)alloc((size_t)N * FH * 4);   // entries, then f2
    __half* ST   = (__half*)alloc((size_t)N * FH * 2);  // t2, then t3 (fp16)
    char*  SX    = (char*)alloc((size_t)N * 256);       // xh (fp16)
    __half* u2   = (__half*)alloc((size_t)N * 32 * 2);
    float* wlin  = (float*)alloc((size_t)N * 4);
    float* wact  = (float*)alloc((size_t)N * 4);
    float* ebuf  = (float*)alloc((size_t)N * 4);
    float* gsum  = (float*)alloc((size_t)G * 4);
    int*   gstart= (int*)alloc((size_t)(G + 1) * 4);
    float* pooled= (float*)alloc((size_t)G * FH * 4);
    int*   bsum  = (int*)alloc(256 * 4);
    int*   boff  = (int*)alloc(256 * 4);
    int*   bcur  = (int*)alloc(NBUK * 4);
    _Float16* WT = (_Float16*)alloc((size_t)118784 * 2); // split-fp16 weights

    __half* xh = (__half*)SX;   // [N,128] fp16 (dead after Y-agg)
    unsigned long long* entries = (unsigned long long*)SA;  // NBUK*ECAP*8 = 16.8MB <= N*FH*4

    hipMemsetAsync(pooled, 0, (size_t)G * FH * 4, stream);

    const int nb = (N + 255) / 256;
    const int NB = (N + 511) / 512;

    wprep_kernel<<<232, 256, 0, stream>>>(W1, W2, W3, A1, A2, WT, bcur);
    ebucket_kernel<<<(E + 2047) / 2048, 256, 0, stream>>>(src, dst, bcur, entries, E, shift);
    ecount_kernel<<<nbuckets, 512, 0, stream>>>(entries, bcur, cnt, N, shift);
    scan1_kernel<<<NB, 256, 0, stream>>>(cnt, bsum, dinv, N);
    scan2_kernel<<<1, 64, 0, stream>>>(bsum, boff, rp + N, NB);
    scan3_kernel<<<NB, 256, 0, stream>>>(cnt, boff, rp, N);
    gstart_kernel<<<1, 128, 0, stream>>>(batch, gstart, N, G);
    ecsr_kernel<<<nbuckets, 512, 0, stream>>>(entries, rp, dinv, cn, N, shift);

    const long n8 = (long)N * FH / 8;
    cvt16_kernel<<<(int)((n8 + 255) / 256), 256, 0, stream>>>(x, xh, n8);

    const int gb64 = (N + 63) / 64;
    const int agb  = (N + 3) / 4;

    // shared layer-1 aggregation: Y = A_hat x
    aggh_kernel<FH, false><<<agb, 256, 0, stream>>>(xh, nullptr, dinv, rp, cn, SY, N);

    // fused layer-1+2 linears: Y -> t2 (ST), u2
    fusedl1_kernel<<<gb64, 256, 0, stream>>>(SY, WT, b1, ba1, (__half*)ST, u2, N);

    // feature branch
    aggh_kernel<FH, true><<<agb, 256, 0, stream>>>(ST, b2, dinv, rp, cn, SA, N);          // f2
    mgemm_kernel<FH, FH, 2><<<gb64, 256, 0, stream>>>(SA, WT + 65536, WT + 81920, nullptr, ST, N); // t3
    aggh_kernel<FH, true><<<agb, 256, 0, stream>>>(ST, b3, dinv, rp, cn, SY, N);          // f3 -> SY

    // attention branch: a2-agg with fused a3 dot -> wlin, then scalar agg
    aggh32a_kernel<<<agb, 256, 0, stream>>>(u2, ba2, A3, dinv, rp, cn, wlin, N);
    agg1_kernel<<<nb, 256, 0, stream>>>(wlin, ba3, dinv, rp, cn, wact, N);

    // fused per-graph softmax + attention pooling
    smexp_kernel<<<G, 256, 0, stream>>>(wact, gstart, gsum, ebuf);
    pool_kernel<<<G * 64, 128, 0, stream>>>(SY, ebuf, gsum, gstart, pooled);

    // MLP (fused)
    mlp_kernel<<<G, 256, 0, stream>>>(pooled, M1, bm1, M2, bm2, out);
}

// Round 11
// 304.494 us; speedup vs baseline: 1.0447x; 1.0145x over previous
//
#include <hip/hip_runtime.h>
#include <hip/hip_fp16.h>
#include <math.h>

// ---------------------------------------------------------------------------
// GCN (3-layer feature + 3-layer attention) + segment softmax + attention
// pooling + MLP.
// R17: producer-side split-fp16. aggY and aggf2 emit PRE-SPLIT fp16 h/l
//     planes (bit-identical to the split the consumer GEMMs did on the
//     fp32 value) -> Y/f2 traffic halves (25.6->12.8MB each) and the
//     latency-bound GEMM staging loops become pure 16B copies (no cvt).
//     Numerically exact: absmax unchanged.
// ---------------------------------------------------------------------------

#define DIN 128
#define FH  128
#define DOUT 256
#define NBUK 128
#define SUBN 512
#define IMGCAP 16384
#define ECAP 16384

typedef float f4 __attribute__((ext_vector_type(4)));
typedef float f32x4 __attribute__((ext_vector_type(4)));
typedef _Float16 h8v __attribute__((ext_vector_type(8)));
typedef _Float16 h4v __attribute__((ext_vector_type(4)));

// ---------------- graph prep ----------------

// scan1 also produces dinv (rsqrt of degree+1) since it already loads cnt.
__global__ __launch_bounds__(256) void scan1_kernel(const int* __restrict__ cnt,
        int* __restrict__ bsum, float* __restrict__ dinv, int n) {
    __shared__ int sm[256];
    int tid = threadIdx.x;
    int base = blockIdx.x * 512;
    int a = (base + tid < n) ? cnt[base + tid] : 0;
    int b = (base + 256 + tid < n) ? cnt[base + 256 + tid] : 0;
    if (base + tid < n)       dinv[base + tid]       = rsqrtf((float)(a + 1));
    if (base + 256 + tid < n) dinv[base + 256 + tid] = rsqrtf((float)(b + 1));
    sm[tid] = a + b;
    __syncthreads();
    for (int off = 128; off > 0; off >>= 1) {
        if (tid < off) sm[tid] += sm[tid + off];
        __syncthreads();
    }
    if (tid == 0) bsum[blockIdx.x] = sm[0];
}

__global__ void scan2_kernel(const int* __restrict__ bsum, int* __restrict__ boff,
                             int* __restrict__ rpN, int nb) {
    if (threadIdx.x == 0) {
        int run = 0;
        for (int i = 0; i < nb; ++i) { boff[i] = run; run += bsum[i]; }
        *rpN = run;
    }
}

__global__ __launch_bounds__(256) void scan3_kernel(const int* __restrict__ cnt,
        const int* __restrict__ boff, int* __restrict__ rp, int n) {
    __shared__ int sm[256];
    int tid = threadIdx.x;
    int base = blockIdx.x * 512;
    int i0 = base + 2 * tid;
    int c0 = (i0 < n) ? cnt[i0] : 0;
    int c1 = (i0 + 1 < n) ? cnt[i0 + 1] : 0;
    int ps = c0 + c1;
    sm[tid] = ps;
    __syncthreads();
    for (int off = 1; off < 256; off <<= 1) {
        int v = (tid >= off) ? sm[tid - off] : 0;
        __syncthreads();
        sm[tid] += v;
        __syncthreads();
    }
    int excl = sm[tid] - ps + boff[blockIdx.x];
    if (i0 < n) rp[i0] = excl;
    if (i0 + 1 < n) rp[i0 + 1] = excl + c0;
}

// Pass A: block-local counting sort by bucket in LDS, then coalesced
// burst-out to per-bucket frontiers (bases at b*ECAP).
__global__ __launch_bounds__(256) void ebucket_kernel(const int* __restrict__ src,
        const int* __restrict__ dst, int* __restrict__ bcur,
        unsigned long long* __restrict__ entries, int E, int shift) {
    __shared__ int lcnt[NBUK], lscan[NBUK], lbase[NBUK], lcur[NBUK];
    __shared__ unsigned long long stage[2048];
    const int tid = threadIdx.x;
    const int e0 = blockIdx.x * 2048;
    if (tid < NBUK) { lcnt[tid] = 0; lcur[tid] = 0; }
    __syncthreads();
    int s_[8], d_[8];
    #pragma unroll
    for (int k = 0; k < 8; ++k) {
        int e = e0 + k * 256 + tid;
        if (e < E) {
            s_[k] = src[e];
            d_[k] = dst[e];
            atomicAdd(&lcnt[d_[k] >> shift], 1);
        } else {
            d_[k] = -1;
        }
    }
    __syncthreads();
    // exclusive scan over NBUK counters (Hillis-Steele, 128 lanes active)
    if (tid < NBUK) lscan[tid] = lcnt[tid];
    __syncthreads();
    for (int off = 1; off < NBUK; off <<= 1) {
        int v = 0;
        if (tid < NBUK && tid >= off) v = lscan[tid - off];
        __syncthreads();
        if (tid < NBUK) lscan[tid] += v;
        __syncthreads();
    }
    if (tid < NBUK) {
        lscan[tid] -= lcnt[tid];   // inclusive -> exclusive
        lbase[tid] = lcnt[tid] ? atomicAdd(&bcur[tid], lcnt[tid]) : 0;
    }
    __syncthreads();
    // scatter into LDS stage, sorted by bucket
    #pragma unroll
    for (int k = 0; k < 8; ++k) {
        if (d_[k] >= 0) {
            int b = d_[k] >> shift;
            int pos = lscan[b] + atomicAdd(&lcur[b], 1);
            stage[pos] = ((unsigned long long)(unsigned)d_[k] << 32) | (unsigned)s_[k];
        }
    }
    __syncthreads();
    // coalesced burst-out: LDS position i -> bucket via binary search
    const int total = min(2048, E - e0);
    for (int i = tid; i < total; i += 256) {
        int lo = 0, hi = NBUK - 1;
        while (lo < hi) {
            int mid = (lo + hi + 1) >> 1;
            if (lscan[mid] <= i) lo = mid; else hi = mid - 1;
        }
        int idx = lbase[lo] + (i - lscan[lo]);
        if (idx < (lo + 1) * ECAP)   // capacity guard (never hit: 91 sigma)
            entries[(size_t)idx] = stage[i];
    }
}

// Degree histogram from bucketed entries: one block per bucket, LDS
// histogram, coalesced cnt write.
__global__ __launch_bounds__(512) void ecount_kernel(
        const unsigned long long* __restrict__ entries,
        const int* __restrict__ bcur, int* __restrict__ cnt, int n, int shift) {
    __shared__ int hist[SUBN];
    const int b = blockIdx.x;
    const int n0 = b << shift;
    if (n0 >= n) return;
    const int n1 = min(n0 + SUBN, n);
    const int tid = threadIdx.x;
    hist[tid] = 0;
    __syncthreads();
    const size_t ebase = (size_t)b * ECAP;
    const int len = min(bcur[b] - b * ECAP, ECAP);
    for (int i = tid; i < len; i += 512)
        atomicAdd(&hist[(int)(entries[ebase + i] >> 32) - n0], 1);
    __syncthreads();
    if (n0 + tid < n1) cnt[n0 + tid] = hist[tid];
}

// Pass B: per-bucket counting sort fully in LDS, contiguous stream-out to cn.
__global__ __launch_bounds__(512) void ecsr_kernel(
        const unsigned long long* __restrict__ entries,
        const int* __restrict__ rp, const float* __restrict__ dinv,
        long long* __restrict__ cn, int n, int shift) {
    __shared__ long long img[IMGCAP];
    __shared__ int hist[SUBN];
    __shared__ int lcur[SUBN];
    __shared__ int sm[SUBN];
    __shared__ float dl[SUBN];
    const int b = blockIdx.x;
    const int n0 = b << shift;
    if (n0 >= n) return;
    const int n1 = min(n0 + (1 << shift), n);
    const int base = rp[n0];
    const int len  = rp[n1] - base;
    const size_t ebase = (size_t)b * ECAP;
    const int tid = threadIdx.x;
    hist[tid] = 0;
    lcur[tid] = 0;
    if (n0 + tid < n1) dl[tid] = dinv[n0 + tid];
    __syncthreads();
    for (int i = tid; i < len; i += 512)
        atomicAdd(&hist[(int)(entries[ebase + i] >> 32) - n0], 1);
    __syncthreads();
    int v = hist[tid];
    sm[tid] = v;
    __syncthreads();
    for (int off = 1; off < SUBN; off <<= 1) {
        int t = (tid >= off) ? sm[tid - off] : 0;
        __syncthreads();
        sm[tid] += t;
        __syncthreads();
    }
    hist[tid] = sm[tid] - v;
    __syncthreads();
    const bool fits = (len <= IMGCAP);
    for (int i = tid; i < len; i += 512) {
        unsigned long long e = entries[ebase + i];
        int d  = (int)(e >> 32) - n0;
        int sx = (int)(unsigned)(e & 0xffffffffu);
        int pos = hist[d] + atomicAdd(&lcur[d], 1);
        float w = dinv[sx] * dl[d];
        long long val = (long long)(unsigned)sx | ((long long)__float_as_int(w) << 32);
        if (fits) img[pos] = val;
        else      cn[base + pos] = val;
    }
    __syncthreads();
    if (fits)
        for (int i = tid; i < len; i += 512) cn[base + i] = img[i];
}

__global__ void gstart_kernel(const int* __restrict__ batch, int* __restrict__ gstart,
                              int n, int g) {
    int t = threadIdx.x;
    if (t > g) return;
    int lo = 0, hi = n;
    while (lo < hi) {
        int mid = (lo + hi) >> 1;
        if (batch[mid] < t) lo = mid + 1; else hi = mid;
    }
    gstart[t] = lo;
}

// fp32 -> fp16 convert (8 elems / thread)
__global__ void cvt16_kernel(const float* __restrict__ in, __half* __restrict__ outh,
                             long n8) {
    long i = (long)blockIdx.x * 256 + threadIdx.x;
    if (i >= n8) return;
    f4 a = ((const f4*)in)[2 * i];
    f4 b = ((const f4*)in)[2 * i + 1];
    __half2 h0 = __float22half2_rn(make_float2(a.x, a.y));
    __half2 h1 = __float22half2_rn(make_float2(a.z, a.w));
    __half2 h2 = __float22half2_rn(make_float2(b.x, b.y));
    __half2 h3 = __float22half2_rn(make_float2(b.z, b.w));
    uint4 st;
    st.x = *(unsigned*)&h0; st.y = *(unsigned*)&h1;
    st.z = *(unsigned*)&h2; st.w = *(unsigned*)&h3;
    ((uint4*)outh)[i] = st;
}

// ---------------- weight prep: split-fp16 transpose ----------------

__device__ __forceinline__ void wsplit(const float* __restrict__ W,
        _Float16* __restrict__ Th, _Float16* __restrict__ Tl,
        int fin, int fout, int i) {
    int r = i / fout, c = i % fout;
    float w = W[i];
    _Float16 h = (_Float16)w;
    Th[c * fin + r] = h;
    Tl[c * fin + r] = (_Float16)(w - (float)h);
}

// WT half-offsets: W1h=0 W1l=16384 W2h=32768 W2l=49152 W3h=65536 W3l=81920
//                  A1h=98304 A1l=106496 A2h=114688 A2l=116736  (total 118784)
__global__ __launch_bounds__(256) void wprep_kernel(const float* __restrict__ W1,
        const float* __restrict__ W2, const float* __restrict__ W3,
        const float* __restrict__ A1, const float* __restrict__ A2,
        _Float16* __restrict__ T, int* __restrict__ bcur) {
    int i = blockIdx.x * 256 + threadIdx.x;
    if (blockIdx.x == 0 && threadIdx.x < NBUK) bcur[threadIdx.x] = threadIdx.x * ECAP;
    if (i < 16384)       wsplit(W1, T,          T + 16384,  128, 128, i);
    else if (i < 32768)  wsplit(W2, T + 32768,  T + 49152,  128, 128, i - 16384);
    else if (i < 49152)  wsplit(W3, T + 65536,  T + 81920,  128, 128, i - 32768);
    else if (i < 57344)  wsplit(A1, T + 98304,  T + 106496, 128, 64,  i - 49152);
    else if (i < 59392)  wsplit(A2, T + 114688, T + 116736, 64,  32,  i - 57344);
}

// ---------------- fused layer-1 linears (split-fp16 MFMA), BM=64 ----------
// R13 structure; staging is now a pure copy from pre-split Yh/Yl planes.

__global__ __launch_bounds__(256) void fusedl1_kernel(const __half* __restrict__ Yh,
        const __half* __restrict__ Yl, const _Float16* __restrict__ T,
        const float* __restrict__ b1, const float* __restrict__ ba1,
        __half* __restrict__ t2, __half* __restrict__ u2, int n) {
    constexpr int LSTR  = 136;
    constexpr int LSTRB = 68;
    __shared__ _Float16 L1[64 * LSTR];     // Yh, then f1 high (alias)
    __shared__ _Float16 L2[64 * LSTR];     // Yl, then f1 low  (alias)
    __shared__ _Float16 Ah_[64 * LSTRB];   // a1 high
    __shared__ _Float16 Al_[64 * LSTRB];   // a1 low
    const int tid  = threadIdx.x;
    const int w    = tid >> 6;
    const int lane = tid & 63;
    const int bk   = (lane >> 4) * 8;
    const int cl   = lane & 15;
    const long row0 = (long)blockIdx.x * 64;

    // stage Yh/Yl -> LDS (pure 16B copies, no conversion)
    for (int i = tid; i < 64 * 16; i += 256) {
        int r = i >> 4, c8 = i & 15;
        long gr = row0 + r;
        uint4 vh = {0u, 0u, 0u, 0u}, vl = {0u, 0u, 0u, 0u};
        if (gr < n) {
            vh = *(const uint4*)&Yh[gr * 128 + c8 * 8];
            vl = *(const uint4*)&Yl[gr * 128 + c8 * 8];
        }
        *(uint4*)&L1[r * LSTR + c8 * 8] = vh;
        *(uint4*)&L2[r * LSTR + c8 * 8] = vl;
    }
    __syncthreads();

    // ---- GEMM1b FIRST: accA = Y@A1, write a1 immediately (short reg life)
    {
        const _Float16* A1h = T + 98304;
        const _Float16* A1l = T + 106496;
        const int ca = w * 16 + cl;
        h8v A1hf[4], A1lf[4];
        #pragma unroll
        for (int kk = 0; kk < 4; ++kk) {
            A1hf[kk] = *(const h8v*)&A1h[ca * 128 + kk * 32 + bk];
            A1lf[kk] = *(const h8v*)&A1l[ca * 128 + kk * 32 + bk];
        }
        f32x4 accA[4];
        #pragma unroll
        for (int rt = 0; rt < 4; ++rt) accA[rt] = (f32x4){0.f,0.f,0.f,0.f};
        #pragma unroll
        for (int rt = 0; rt < 4; ++rt) {
            int r = rt * 16 + cl;
            #pragma unroll
            for (int kk = 0; kk < 4; ++kk) {
                h8v ah = *(const h8v*)&L1[r * LSTR + kk * 32 + bk];
                h8v al = *(const h8v*)&L2[r * LSTR + kk * 32 + bk];
                accA[rt] = __builtin_amdgcn_mfma_f32_16x16x32_f16(ah, A1hf[kk], accA[rt], 0, 0, 0);
                accA[rt] = __builtin_amdgcn_mfma_f32_16x16x32_f16(ah, A1lf[kk], accA[rt], 0, 0, 0);
                accA[rt] = __builtin_amdgcn_mfma_f32_16x16x32_f16(al, A1hf[kk], accA[rt], 0, 0, 0);
            }
        }
        float bv = ba1[ca];
        #pragma unroll
        for (int rt = 0; rt < 4; ++rt) {
            int rowb = rt * 16 + (lane >> 4) * 4;
            #pragma unroll
            for (int j = 0; j < 4; ++j) {
                float v = fmaxf(accA[rt][j] + bv, 0.f);
                _Float16 h = (_Float16)v;
                Ah_[(rowb + j) * LSTRB + ca] = h;
                Al_[(rowb + j) * LSTRB + ca] = (_Float16)(v - (float)h);
            }
        }
    }

    // ---- GEMM1a: accF = Y@W1 (wave w owns cols [w*32, w*32+32))
    f32x4 accF[4][2];
    {
        const _Float16* W1h = T;
        const _Float16* W1l = T + 16384;
        h8v Bh[2][4], Bl[2][4];
        #pragma unroll
        for (int ct = 0; ct < 2; ++ct) {
            int c = w * 32 + ct * 16 + cl;
            #pragma unroll
            for (int kk = 0; kk < 4; ++kk) {
                Bh[ct][kk] = *(const h8v*)&W1h[c * 128 + kk * 32 + bk];
                Bl[ct][kk] = *(const h8v*)&W1l[c * 128 + kk * 32 + bk];
            }
        }
        #pragma unroll
        for (int rt = 0; rt < 4; ++rt)
            #pragma unroll
            for (int ct = 0; ct < 2; ++ct) accF[rt][ct] = (f32x4){0.f,0.f,0.f,0.f};
        #pragma unroll
        for (int rt = 0; rt < 4; ++rt) {
            int r = rt * 16 + cl;
            #pragma unroll
            for (int kk = 0; kk < 4; ++kk) {
                h8v ah = *(const h8v*)&L1[r * LSTR + kk * 32 + bk];
                h8v al = *(const h8v*)&L2[r * LSTR + kk * 32 + bk];
                #pragma unroll
                for (int ct = 0; ct < 2; ++ct) {
                    accF[rt][ct] = __builtin_amdgcn_mfma_f32_16x16x32_f16(ah, Bh[ct][kk], accF[rt][ct], 0, 0, 0);
                    accF[rt][ct] = __builtin_amdgcn_mfma_f32_16x16x32_f16(ah, Bl[ct][kk], accF[rt][ct], 0, 0, 0);
                    accF[rt][ct] = __builtin_amdgcn_mfma_f32_16x16x32_f16(al, Bh[ct][kk], accF[rt][ct], 0, 0, 0);
                }
            }
        }
    }
    __syncthreads();   // all Y reads complete -> safe to overwrite L1/L2

    // ---- write f1 = relu(accF+b1) -> L1/L2 (alias)
    #pragma unroll
    for (int rt = 0; rt < 4; ++rt) {
        int rowb = rt * 16 + (lane >> 4) * 4;
        #pragma unroll
        for (int ct = 0; ct < 2; ++ct) {
            int col = w * 32 + ct * 16 + cl;
            float bv = b1[col];
            #pragma unroll
            for (int j = 0; j < 4; ++j) {
                float v = fmaxf(accF[rt][ct][j] + bv, 0.f);
                _Float16 h = (_Float16)v;
                L1[(rowb + j) * LSTR + col] = h;
                L2[(rowb + j) * LSTR + col] = (_Float16)(v - (float)h);
            }
        }
    }
    __syncthreads();

    // ---- GEMM2a: t2 = f1@W2 (fp16 out; wave w owns cols [w*32, w*32+32))
    {
        const _Float16* W2h = T + 32768;
        const _Float16* W2l = T + 49152;
        h8v Bh[2][4], Bl[2][4];
        #pragma unroll
        for (int ct = 0; ct < 2; ++ct) {
            int c = w * 32 + ct * 16 + cl;
            #pragma unroll
            for (int kk = 0; kk < 4; ++kk) {
                Bh[ct][kk] = *(const h8v*)&W2h[c * 128 + kk * 32 + bk];
                Bl[ct][kk] = *(const h8v*)&W2l[c * 128 + kk * 32 + bk];
            }
        }
        f32x4 acc[4][2];
        #pragma unroll
        for (int rt = 0; rt < 4; ++rt)
            #pragma unroll
            for (int ct = 0; ct < 2; ++ct) acc[rt][ct] = (f32x4){0.f,0.f,0.f,0.f};
        #pragma unroll
        for (int rt = 0; rt < 4; ++rt) {
            int r = rt * 16 + cl;
            #pragma unroll
            for (int kk = 0; kk < 4; ++kk) {
                h8v ah = *(const h8v*)&L1[r * LSTR + kk * 32 + bk];
                h8v al = *(const h8v*)&L2[r * LSTR + kk * 32 + bk];
                #pragma unroll
                for (int ct = 0; ct < 2; ++ct) {
                    acc[rt][ct] = __builtin_amdgcn_mfma_f32_16x16x32_f16(ah, Bh[ct][kk], acc[rt][ct], 0, 0, 0);
                    acc[rt][ct] = __builtin_amdgcn_mfma_f32_16x16x32_f16(ah, Bl[ct][kk], acc[rt][ct], 0, 0, 0);
                    acc[rt][ct] = __builtin_amdgcn_mfma_f32_16x16x32_f16(al, Bh[ct][kk], acc[rt][ct], 0, 0, 0);
                }
            }
        }
        #pragma unroll
        for (int rt = 0; rt < 4; ++rt) {
            long rbase = row0 + rt * 16 + (lane >> 4) * 4;
            #pragma unroll
            for (int ct = 0; ct < 2; ++ct) {
                int col = w * 32 + ct * 16 + cl;
                #pragma unroll
                for (int j = 0; j < 4; ++j) {
                    long r = rbase + j;
                    if (r < n) t2[r * 128 + col] = __float2half(acc[rt][ct][j]);
                }
            }
        }
    }

    // ---- GEMM2b: u2 = a1@A2 (fp16 out; wave w owns rows [w*16, w*16+16))
    {
        const _Float16* A2h = T + 114688;
        const _Float16* A2l = T + 116736;
        h8v Bh[2][2], Bl[2][2];
        #pragma unroll
        for (int ct = 0; ct < 2; ++ct) {
            int c = ct * 16 + cl;
            #pragma unroll
            for (int kk = 0; kk < 2; ++kk) {
                Bh[ct][kk] = *(const h8v*)&A2h[c * 64 + kk * 32 + bk];
                Bl[ct][kk] = *(const h8v*)&A2l[c * 64 + kk * 32 + bk];
            }
        }
        f32x4 acc[2];
        acc[0] = (f32x4){0.f,0.f,0.f,0.f};
        acc[1] = (f32x4){0.f,0.f,0.f,0.f};
        const int r = w * 16 + cl;
        #pragma unroll
        for (int kk = 0; kk < 2; ++kk) {
            h8v ah = *(const h8v*)&Ah_[r * LSTRB + kk * 32 + bk];
            h8v al = *(const h8v*)&Al_[r * LSTRB + kk * 32 + bk];
            #pragma unroll
            for (int ct = 0; ct < 2; ++ct) {
                acc[ct] = __builtin_amdgcn_mfma_f32_16x16x32_f16(ah, Bh[ct][kk], acc[ct], 0, 0, 0);
                acc[ct] = __builtin_amdgcn_mfma_f32_16x16x32_f16(ah, Bl[ct][kk], acc[ct], 0, 0, 0);
                acc[ct] = __builtin_amdgcn_mfma_f32_16x16x32_f16(al, Bh[ct][kk], acc[ct], 0, 0, 0);
            }
        }
        long rbase = row0 + w * 16 + (lane >> 4) * 4;
        #pragma unroll
        for (int ct = 0; ct < 2; ++ct) {
            int col = ct * 16 + cl;
            #pragma unroll
            for (int j = 0; j < 4; ++j) {
                long rr = rbase + j;
                if (rr < n) u2[rr * 32 + col] = __float2half(acc[ct][j]);
            }
        }
    }
}

// ---------------- t3 GEMM: t3 = f2@W3 (fp16 out), split-plane input ------
__global__ __launch_bounds__(256) void t3gemm_kernel(const __half* __restrict__ Fh,
        const __half* __restrict__ Fl, const _Float16* __restrict__ Wh,
        const _Float16* __restrict__ Wl, __half* __restrict__ C, int n) {
    constexpr int LSTR = 136;
    __shared__ _Float16 Ahs[64 * LSTR];
    __shared__ _Float16 Als[64 * LSTR];
    const int tid  = threadIdx.x;
    const int w    = tid >> 6;
    const int lane = tid & 63;
    const int bk   = (lane >> 4) * 8;
    const int cl   = lane & 15;
    const long row0 = (long)blockIdx.x * 64;

    // stage f2h/f2l -> LDS (pure 16B copies)
    for (int i = tid; i < 64 * 16; i += 256) {
        int r = i >> 4, c8 = i & 15;
        long gr = row0 + r;
        uint4 vh = {0u, 0u, 0u, 0u}, vl = {0u, 0u, 0u, 0u};
        if (gr < n) {
            vh = *(const uint4*)&Fh[gr * 128 + c8 * 8];
            vl = *(const uint4*)&Fl[gr * 128 + c8 * 8];
        }
        *(uint4*)&Ahs[r * LSTR + c8 * 8] = vh;
        *(uint4*)&Als[r * LSTR + c8 * 8] = vl;
    }

    h8v Bh[2][4], Bl[2][4];
    #pragma unroll
    for (int ct = 0; ct < 2; ++ct) {
        int c = w * 32 + ct * 16 + cl;
        #pragma unroll
        for (int kk = 0; kk < 4; ++kk) {
            Bh[ct][kk] = *(const h8v*)&Wh[c * 128 + kk * 32 + bk];
            Bl[ct][kk] = *(const h8v*)&Wl[c * 128 + kk * 32 + bk];
        }
    }
    __syncthreads();

    f32x4 acc[4][2];
    #pragma unroll
    for (int rt = 0; rt < 4; ++rt)
        #pragma unroll
        for (int ct = 0; ct < 2; ++ct) acc[rt][ct] = (f32x4){0.f,0.f,0.f,0.f};
    #pragma unroll
    for (int rt = 0; rt < 4; ++rt) {
        int r = rt * 16 + cl;
        #pragma unroll
        for (int kk = 0; kk < 4; ++kk) {
            h8v ah = *(const h8v*)&Ahs[r * LSTR + kk * 32 + bk];
            h8v al = *(const h8v*)&Als[r * LSTR + kk * 32 + bk];
            #pragma unroll
            for (int ct = 0; ct < 2; ++ct) {
                acc[rt][ct] = __builtin_amdgcn_mfma_f32_16x16x32_f16(ah, Bh[ct][kk], acc[rt][ct], 0, 0, 0);
                acc[rt][ct] = __builtin_amdgcn_mfma_f32_16x16x32_f16(ah, Bl[ct][kk], acc[rt][ct], 0, 0, 0);
                acc[rt][ct] = __builtin_amdgcn_mfma_f32_16x16x32_f16(al, Bh[ct][kk], acc[rt][ct], 0, 0, 0);
            }
        }
    }
    #pragma unroll
    for (int rt = 0; rt < 4; ++rt) {
        long rbase = row0 + rt * 16 + (lane >> 4) * 4;
        #pragma unroll
        for (int ct = 0; ct < 2; ++ct) {
            int col = w * 32 + ct * 16 + cl;
            #pragma unroll
            for (int j = 0; j < 4; ++j) {
                long r = rbase + j;
                if (r < n) C[r * 128 + col] = __float2half(acc[rt][ct][j]);
            }
        }
    }
}

// ---------------- fp16-gather aggregation ----------------

__device__ __forceinline__ void hacc8(float acc[8], uint4 u, float w) {
    __half2 h; float2 f;
    h = *(__half2*)&u.x; f = __half22float2(h); acc[0] += w * f.x; acc[1] += w * f.y;
    h = *(__half2*)&u.y; f = __half22float2(h); acc[2] += w * f.x; acc[3] += w * f.y;
    h = *(__half2*)&u.z; f = __half22float2(h); acc[4] += w * f.x; acc[5] += w * f.y;
    h = *(__half2*)&u.w; f = __half22float2(h); acc[6] += w * f.x; acc[7] += w * f.y;
}

// F=128 aggregation with SPLIT fp16 h/l plane output (bit-identical to the
// consumer-side split the GEMMs previously performed on the fp32 value).
template<bool BR>
__global__ __launch_bounds__(256) void agghs_kernel(const __half* __restrict__ tin,
        const float* __restrict__ bias, const float* __restrict__ dinv,
        const int* __restrict__ rp, const long long* __restrict__ cn,
        __half* __restrict__ outh, __half* __restrict__ outl, int n) {
    constexpr int LPR   = 16;
    constexpr int SLOTS = 4;
    const int lane = threadIdx.x & 63;
    const int node = blockIdx.x * 4 + (threadIdx.x >> 6);
    if (node >= n) return;
    const int l    = lane % LPR;
    const int slot = lane / LPR;
    const uint4* base = (const uint4*)tin + l;
    const int e0 = rp[node], e1 = rp[node + 1];
    float acc[8] = {0.f, 0.f, 0.f, 0.f, 0.f, 0.f, 0.f, 0.f};
    if (slot == 0) {
        float di = dinv[node];
        uint4 u = base[(size_t)node * LPR];
        hacc8(acc, u, di * di);
    }
    int p = e0 + slot;
    for (; p + 3 * SLOTS < e1; p += 4 * SLOTS) {
        long long r0 = __builtin_nontemporal_load(cn + p);
        long long r1 = __builtin_nontemporal_load(cn + p + SLOTS);
        long long r2 = __builtin_nontemporal_load(cn + p + 2 * SLOTS);
        long long r3 = __builtin_nontemporal_load(cn + p + 3 * SLOTS);
        uint4 u0 = base[(size_t)(unsigned)r0 * LPR];
        uint4 u1 = base[(size_t)(unsigned)r1 * LPR];
        uint4 u2 = base[(size_t)(unsigned)r2 * LPR];
        uint4 u3 = base[(size_t)(unsigned)r3 * LPR];
        hacc8(acc, u0, __int_as_float((int)(r0 >> 32)));
        hacc8(acc, u1, __int_as_float((int)(r1 >> 32)));
        hacc8(acc, u2, __int_as_float((int)(r2 >> 32)));
        hacc8(acc, u3, __int_as_float((int)(r3 >> 32)));
    }
    for (; p + SLOTS < e1; p += 2 * SLOTS) {
        long long r0 = __builtin_nontemporal_load(cn + p);
        long long r1 = __builtin_nontemporal_load(cn + p + SLOTS);
        uint4 u0 = base[(size_t)(unsigned)r0 * LPR];
        uint4 u1 = base[(size_t)(unsigned)r1 * LPR];
        hacc8(acc, u0, __int_as_float((int)(r0 >> 32)));
        hacc8(acc, u1, __int_as_float((int)(r1 >> 32)));
    }
    if (p < e1) {
        long long r0 = __builtin_nontemporal_load(cn + p);
        uint4 u0 = base[(size_t)(unsigned)r0 * LPR];
        hacc8(acc, u0, __int_as_float((int)(r0 >> 32)));
    }
    #pragma unroll
    for (int off = 32; off >= LPR; off >>= 1) {
        #pragma unroll
        for (int j = 0; j < 8; ++j) acc[j] += __shfl_xor(acc[j], off);
    }
    if (slot == 0) {
        h8v hv, lv;
        #pragma unroll
        for (int j = 0; j < 8; ++j) {
            float v = BR ? fmaxf(acc[j] + bias[l * 8 + j], 0.f) : acc[j];
            _Float16 h = (_Float16)v;
            hv[j] = h;
            lv[j] = (_Float16)(v - (float)h);
        }
        __builtin_nontemporal_store(hv, (h8v*)(outh + (size_t)node * FH + l * 8));
        __builtin_nontemporal_store(lv, (h8v*)(outl + (size_t)node * FH + l * 8));
    }
}

// plain F=128 aggregation with fp32 output (f3, consumed by pooling)
template<int F, bool BR>
__global__ __launch_bounds__(256) void aggh_kernel(const __half* __restrict__ tin,
        const float* __restrict__ bias, const float* __restrict__ dinv,
        const int* __restrict__ rp, const long long* __restrict__ cn,
        float* __restrict__ out, int n) {
    constexpr int LPR   = F / 8;
    constexpr int SLOTS = 64 / LPR;
    const int lane = threadIdx.x & 63;
    const int node = blockIdx.x * 4 + (threadIdx.x >> 6);
    if (node >= n) return;
    const int l    = lane % LPR;
    const int slot = lane / LPR;
    const uint4* base = (const uint4*)tin + l;
    const int e0 = rp[node], e1 = rp[node + 1];
    float acc[8] = {0.f, 0.f, 0.f, 0.f, 0.f, 0.f, 0.f, 0.f};
    if (slot == 0) {
        float di = dinv[node];
        uint4 u = base[(size_t)node * LPR];
        hacc8(acc, u, di * di);
    }
    int p = e0 + slot;
    for (; p + 3 * SLOTS < e1; p += 4 * SLOTS) {
        long long r0 = __builtin_nontemporal_load(cn + p);
        long long r1 = __builtin_nontemporal_load(cn + p + SLOTS);
        long long r2 = __builtin_nontemporal_load(cn + p + 2 * SLOTS);
        long long r3 = __builtin_nontemporal_load(cn + p + 3 * SLOTS);
        uint4 u0 = base[(size_t)(unsigned)r0 * LPR];
        uint4 u1 = base[(size_t)(unsigned)r1 * LPR];
        uint4 u2 = base[(size_t)(unsigned)r2 * LPR];
        uint4 u3 = base[(size_t)(unsigned)r3 * LPR];
        hacc8(acc, u0, __int_as_float((int)(r0 >> 32)));
        hacc8(acc, u1, __int_as_float((int)(r1 >> 32)));
        hacc8(acc, u2, __int_as_float((int)(r2 >> 32)));
        hacc8(acc, u3, __int_as_float((int)(r3 >> 32)));
    }
    for (; p + SLOTS < e1; p += 2 * SLOTS) {
        long long r0 = __builtin_nontemporal_load(cn + p);
        long long r1 = __builtin_nontemporal_load(cn + p + SLOTS);
        uint4 u0 = base[(size_t)(unsigned)r0 * LPR];
        uint4 u1 = base[(size_t)(unsigned)r1 * LPR];
        hacc8(acc, u0, __int_as_float((int)(r0 >> 32)));
        hacc8(acc, u1, __int_as_float((int)(r1 >> 32)));
    }
    if (p < e1) {
        long long r0 = __builtin_nontemporal_load(cn + p);
        uint4 u0 = base[(size_t)(unsigned)r0 * LPR];
        hacc8(acc, u0, __int_as_float((int)(r0 >> 32)));
    }
    #pragma unroll
    for (int off = 32; off >= LPR; off >>= 1) {
        #pragma unroll
        for (int j = 0; j < 8; ++j) acc[j] += __shfl_xor(acc[j], off);
    }
    if (slot == 0) {
        if (BR) {
            #pragma unroll
            for (int j = 0; j < 8; ++j)
                acc[j] = fmaxf(acc[j] + bias[l * 8 + j], 0.f);
        }
        f4 lo = {acc[0], acc[1], acc[2], acc[3]};
        f4 hi = {acc[4], acc[5], acc[6], acc[7]};
        float* o = out + (size_t)node * F + l * 8;
        __builtin_nontemporal_store(lo, (f4*)o);
        __builtin_nontemporal_store(hi, (f4*)(o + 4));
    }
}

// a2-aggregation (F=32) with fused a3 dot: wlin[node] = relu(agg+ba2) . A3
__global__ __launch_bounds__(256) void aggh32a_kernel(const __half* __restrict__ tin,
        const float* __restrict__ ba2, const float* __restrict__ A3,
        const float* __restrict__ dinv, const int* __restrict__ rp,
        const long long* __restrict__ cn, float* __restrict__ wlin, int n) {
    constexpr int LPR   = 4;
    constexpr int SLOTS = 16;
    const int lane = threadIdx.x & 63;
    const int node = blockIdx.x * 4 + (threadIdx.x >> 6);
    if (node >= n) return;
    const int l    = lane % LPR;
    const int slot = lane / LPR;
    const uint4* base = (const uint4*)tin + l;
    const int e0 = rp[node], e1 = rp[node + 1];
    float acc[8] = {0.f, 0.f, 0.f, 0.f, 0.f, 0.f, 0.f, 0.f};
    if (slot == 0) {
        float di = dinv[node];
        uint4 u = base[(size_t)node * LPR];
        hacc8(acc, u, di * di);
    }
    int p = e0 + slot;
    for (; p + SLOTS < e1; p += 2 * SLOTS) {
        long long r0 = __builtin_nontemporal_load(cn + p);
        long long r1 = __builtin_nontemporal_load(cn + p + SLOTS);
        uint4 u0 = base[(size_t)(unsigned)r0 * LPR];
        uint4 u1 = base[(size_t)(unsigned)r1 * LPR];
        hacc8(acc, u0, __int_as_float((int)(r0 >> 32)));
        hacc8(acc, u1, __int_as_float((int)(r1 >> 32)));
    }
    if (p < e1) {
        long long r0 = __builtin_nontemporal_load(cn + p);
        uint4 u0 = base[(size_t)(unsigned)r0 * LPR];
        hacc8(acc, u0, __int_as_float((int)(r0 >> 32)));
    }
    #pragma unroll
    for (int off = 32; off >= LPR; off >>= 1) {
        #pragma unroll
        for (int j = 0; j < 8; ++j) acc[j] += __shfl_xor(acc[j], off);
    }
    if (slot == 0) {
        float part = 0.f;
        #pragma unroll
        for (int j = 0; j < 8; ++j)
            part += fmaxf(acc[j] + ba2[l * 8 + j], 0.f) * A3[l * 8 + j];
        part += __shfl_xor(part, 1);
        part += __shfl_xor(part, 2);
        if (l == 0) wlin[node] = part;
    }
}

// F=1 aggregation for the attention scalar
__global__ void agg1_kernel(const float* __restrict__ tin, const float* __restrict__ bias,
        const float* __restrict__ dinv, const int* __restrict__ rp,
        const long long* __restrict__ cn, float* __restrict__ out, int n) {
    int i = blockIdx.x * 256 + threadIdx.x;
    if (i >= n) return;
    float di = dinv[i];
    float acc = di * di * tin[i];
    int e0 = rp[i], e1 = rp[i + 1];
    int p = e0;
    float a0 = 0.f, a1 = 0.f, a2 = 0.f, a3 = 0.f;
    for (; p + 3 < e1; p += 4) {
        long long r0 = __builtin_nontemporal_load(cn + p);
        long long r1 = __builtin_nontemporal_load(cn + p + 1);
        long long r2 = __builtin_nontemporal_load(cn + p + 2);
        long long r3 = __builtin_nontemporal_load(cn + p + 3);
        a0 += __int_as_float((int)(r0 >> 32)) * tin[(int)(unsigned)r0];
        a1 += __int_as_float((int)(r1 >> 32)) * tin[(int)(unsigned)r1];
        a2 += __int_as_float((int)(r2 >> 32)) * tin[(int)(unsigned)r2];
        a3 += __int_as_float((int)(r3 >> 32)) * tin[(int)(unsigned)r3];
    }
    for (; p < e1; ++p) {
        long long r0 = __builtin_nontemporal_load(cn + p);
        a0 += __int_as_float((int)(r0 >> 32)) * tin[(int)(unsigned)r0];
    }
    acc += a0 + a1 + a2 + a3 + bias[0];
    out[i] = acc > 0.f ? acc : 0.f;
}

// ---------------- fused per-graph softmax (max + exp + sum) ----------------

__global__ __launch_bounds__(256) void smexp_kernel(const float* __restrict__ w,
        const int* __restrict__ gstart, float* __restrict__ gsum,
        float* __restrict__ e) {
    const int g = blockIdx.x;
    const int a = gstart[g], b = gstart[g + 1];
    const int tid = threadIdx.x;
    __shared__ float red[4];
    float m = 0.f;                       // w >= 0 (post-relu)
    for (int i = a + tid; i < b; i += 256) m = fmaxf(m, w[i]);
    #pragma unroll
    for (int off = 32; off > 0; off >>= 1) m = fmaxf(m, __shfl_xor(m, off));
    if ((tid & 63) == 0) red[tid >> 6] = m;
    __syncthreads();
    m = fmaxf(fmaxf(red[0], red[1]), fmaxf(red[2], red[3]));
    float s = 0.f;
    for (int i = a + tid; i < b; i += 256) {
        float ex = expf(w[i] - m);
        e[i] = ex;
        s += ex;
    }
    #pragma unroll
    for (int off = 32; off > 0; off >>= 1) s += __shfl_xor(s, off);
    __syncthreads();
    if ((tid & 63) == 0) red[tid >> 6] = s;
    __syncthreads();
    if (tid == 0) gsum[g] = red[0] + red[1] + red[2] + red[3];
}

// ---------------- attention pooling ----------------

__global__ __launch_bounds__(128) void pool_kernel(const float* __restrict__ f3,
        const float* __restrict__ e, const float* __restrict__ gsum,
        const int* __restrict__ gstart, float* __restrict__ pooled) {
    constexpr int SPG = 64;
    const int g = blockIdx.x / SPG, s = blockIdx.x % SPG;
    const int a = gstart[g], bnd = gstart[g + 1];
    const int len = bnd - a;
    if (len <= 0) return;
    const int chunk = (len + SPG - 1) / SPG;
    const int lo = a + s * chunk;
    const int hi = min(lo + chunk, bnd);
    if (lo >= hi) return;
    const float inv = 1.f / (gsum[g] + 1e-16f);
    const int tid = threadIdx.x;
    const int lane4 = tid & 31;
    const int rs    = tid >> 5;
    f4 acc = {0.f, 0.f, 0.f, 0.f};
    for (int i = lo + rs; i < hi; i += 4) {
        float w = e[i] * inv;
        f4 v = *(const f4*)&f3[(size_t)i * FH + lane4 * 4];
        acc.x += w * v.x; acc.y += w * v.y;
        acc.z += w * v.z; acc.w += w * v.w;
    }
    acc.x += __shfl_xor(acc.x, 32);
    acc.y += __shfl_xor(acc.y, 32);
    acc.z += __shfl_xor(acc.z, 32);
    acc.w += __shfl_xor(acc.w, 32);
    __shared__ float sm[128];
    if (tid >= 64 && tid < 96) *(f4*)&sm[(tid - 64) * 4] = acc;
    __syncthreads();
    if (tid < 32) {
        f4 o = *(f4*)&sm[tid * 4];
        o.x += acc.x; o.y += acc.y; o.z += acc.z; o.w += acc.w;
        float* dst = &pooled[g * FH + tid * 4];
        atomicAdd(dst + 0, o.x);
        atomicAdd(dst + 1, o.y);
        atomicAdd(dst + 2, o.z);
        atomicAdd(dst + 3, o.w);
    }
}

// ---------------- MLP (both layers fused; one block per graph) ----------------

__global__ __launch_bounds__(256) void mlp_kernel(const float* __restrict__ pooled,
        const float* __restrict__ M1, const float* __restrict__ bm1,
        const float* __restrict__ M2, const float* __restrict__ bm2,
        float* __restrict__ out) {
    __shared__ float pr[FH];
    __shared__ float hr[FH];
    int g = blockIdx.x, j = threadIdx.x;
    if (j < FH) pr[j] = pooled[g * FH + j];
    __syncthreads();
    if (j < FH) {
        float acc = bm1[j];
        #pragma unroll 8
        for (int k = 0; k < FH; ++k) acc += pr[k] * M1[k * FH + j];
        hr[j] = acc > 0.f ? acc : 0.f;
    }
    __syncthreads();
    float acc = bm2[j];
    #pragma unroll 8
    for (int k = 0; k < FH; ++k) acc += hr[k] * M2[k * DOUT + j];
    out[g * DOUT + j] = acc;
}

// ---------------------------------------------------------------------------

extern "C" void kernel_launch(void* const* d_in, const int* in_sizes, int n_in,
                              void* d_out, int out_size, void* d_ws, size_t ws_size,
                              hipStream_t stream) {
    const float* x   = (const float*)d_in[0];
    const int*   ei  = (const int*)d_in[1];
    const int*   batch = (const int*)d_in[2];
    const float* W1  = (const float*)d_in[3];
    const float* b1  = (const float*)d_in[4];
    const float* W2  = (const float*)d_in[5];
    const float* b2  = (const float*)d_in[6];
    const float* W3  = (const float*)d_in[7];
    const float* b3  = (const float*)d_in[8];
    const float* A1  = (const float*)d_in[9];
    const float* ba1 = (const float*)d_in[10];
    const float* A2  = (const float*)d_in[11];
    const float* ba2 = (const float*)d_in[12];
    const float* A3  = (const float*)d_in[13];
    const float* ba3 = (const float*)d_in[14];
    const float* M1  = (const float*)d_in[15];
    const float* bm1 = (const float*)d_in[16];
    const float* M2  = (const float*)d_in[17];
    const float* bm2 = (const float*)d_in[18];

    const int N = in_sizes[0] / DIN;
    const int E = in_sizes[1] / 2;
    const int G = out_size / DOUT;
    const int* src = ei;
    const int* dst = ei + E;
    float* out = (float*)d_out;

    // bucket shift: smallest s with ceil(N / 2^s) <= NBUK (=9 for N=50000)
    int shift = 9;
    while (((N + (1 << shift) - 1) >> shift) > NBUK) ++shift;
    const int nbuckets = (N + (1 << shift) - 1) >> shift;

    // workspace carve (aliased; see lifetime notes)
    char* p = (char*)d_ws;
    auto alloc = [&](size_t bytes) -> void* {
        void* r = (void*)p;
        p += (bytes + 255) & ~(size_t)255;
        return r;
    };
    float* dinv  = (float*)alloc((size_t)N * 4);
    int*   cnt   = (int*)alloc((size_t)N * 4);
    int*   rp    = (int*)alloc((size_t)(N + 1) * 4);
    long long* cn = (long long*)alloc((size_t)E * 8);
    float* SY    = (float*)alloc((size_t)N * FH * 4);   // Yh/Yl planes, then f3 (fp32)
    float* SA    = (float*)alloc((size_t)N * FH * 4);   // entries, then f2h/f2l planes
    __half* ST   = (__half*)alloc((size_t)N * FH * 2);  // t2, then t3 (fp16)
    char*  SX    = (char*)alloc((size_t)N * 256);       // xh (fp16)
    __half* u2   = (__half*)alloc((size_t)N * 32 * 2);
    float* wlin  = (float*)alloc((size_t)N * 4);
    float* wact  = (float*)alloc((size_t)N * 4);
    float* ebuf  = (float*)alloc((size_t)N * 4);
    float* gsum  = (float*)alloc((size_t)G * 4);
    int*   gstart= (int*)alloc((size_t)(G + 1) * 4);
    float* pooled= (float*)alloc((size_t)G * FH * 4);
    int*   bsum  = (int*)alloc(256 * 4);
    int*   boff  = (int*)alloc(256 * 4);
    int*   bcur  = (int*)alloc(NBUK * 4);
    _Float16* WT = (_Float16*)alloc((size_t)118784 * 2); // split-fp16 weights

    __half* xh  = (__half*)SX;                       // [N,128] fp16 (dead after Y-agg)
    __half* Yh  = (__half*)SY;                       // [N,128] fp16 high plane
    __half* Yl  = Yh + (size_t)N * FH;               // [N,128] fp16 low plane
    __half* F2h = (__half*)SA;                       // f2 high plane (entries dead)
    __half* F2l = F2h + (size_t)N * FH;              // f2 low plane
    unsigned long long* entries = (unsigned long long*)SA;  // 16.8MB <= N*FH*4

    hipMemsetAsync(pooled, 0, (size_t)G * FH * 4, stream);

    const int nb = (N + 255) / 256;
    const int NB = (N + 511) / 512;

    wprep_kernel<<<232, 256, 0, stream>>>(W1, W2, W3, A1, A2, WT, bcur);
    ebucket_kernel<<<(E + 2047) / 2048, 256, 0, stream>>>(src, dst, bcur, entries, E, shift);
    ecount_kernel<<<nbuckets, 512, 0, stream>>>(entries, bcur, cnt, N, shift);
    scan1_kernel<<<NB, 256, 0, stream>>>(cnt, bsum, dinv, N);
    scan2_kernel<<<1, 64, 0, stream>>>(bsum, boff, rp + N, NB);
    scan3_kernel<<<NB, 256, 0, stream>>>(cnt, boff, rp, N);
    gstart_kernel<<<1, 128, 0, stream>>>(batch, gstart, N, G);
    ecsr_kernel<<<nbuckets, 512, 0, stream>>>(entries, rp, dinv, cn, N, shift);

    const long n8 = (long)N * FH / 8;
    cvt16_kernel<<<(int)((n8 + 255) / 256), 256, 0, stream>>>(x, xh, n8);

    const int gb64 = (N + 63) / 64;
    const int agb  = (N + 3) / 4;

    // shared layer-1 aggregation: Y = A_hat x  -> pre-split Yh/Yl planes
    agghs_kernel<false><<<agb, 256, 0, stream>>>(xh, nullptr, dinv, rp, cn, Yh, Yl, N);

    // fused layer-1+2 linears: Y -> t2 (ST), u2
    fusedl1_kernel<<<gb64, 256, 0, stream>>>(Yh, Yl, WT, b1, ba1, (__half*)ST, u2, N);

    // feature branch: f2 agg -> pre-split planes, then t3 = f2@W3
    agghs_kernel<true><<<agb, 256, 0, stream>>>(ST, b2, dinv, rp, cn, F2h, F2l, N);
    t3gemm_kernel<<<gb64, 256, 0, stream>>>(F2h, F2l, WT + 65536, WT + 81920, (__half*)ST, N);
    aggh_kernel<FH, true><<<agb, 256, 0, stream>>>(ST, b3, dinv, rp, cn, SY, N);  // f3 -> SY (fp32)

    // attention branch: a2-agg with fused a3 dot -> wlin, then scalar agg
    aggh32a_kernel<<<agb, 256, 0, stream>>>(u2, ba2, A3, dinv, rp, cn, wlin, N);
    agg1_kernel<<<nb, 256, 0, stream>>>(wlin, ba3, dinv, rp, cn, wact, N);

    // fused per-graph softmax + attention pooling
    smexp_kernel<<<G, 256, 0, stream>>>(wact, gstart, gsum, ebuf);
    pool_kernel<<<G * 64, 128, 0, stream>>>(SY, ebuf, gsum, gstart, pooled);

    // MLP (fused)
    mlp_kernel<<<G, 256, 0, stream>>>(pooled, M1, bm1, M2, bm2, out);
}